// Round 1
// baseline (609.760 us; speedup 1.0000x reference)
//
#include <hip/hip_runtime.h>
#include <math.h>

#define B_ 4
#define L_ 8192
#define D_ 512
#define M_ 256
#define NR_ (B_ * L_)                  // 32768 rows
#define SCALE_ 0.21022410381342864f    // 512^{-1/4}
#define EPS_ 1e-6f
#define RSQM_ 0.0625f                  // 1/sqrt(256)

// ---------------------------------------------------------------------------
// dash = SCALE * X @ proj^T   (NR x 256) = (NR x 512) @ (256 x 512)^T
// tile: 64 rows x 256 cols (full M), 256 threads, each thread 4x16 accs.
// ---------------------------------------------------------------------------
__global__ __launch_bounds__(256) void dash_gemm(const float* __restrict__ X,
                                                 const float* __restrict__ P,
                                                 float* __restrict__ dash) {
    __shared__ float Xs[64][36];    // pad 36: ty-reads hit distinct banks
    __shared__ float Ps[256][36];
    const int t  = threadIdx.x;
    const int ty = t >> 4;          // 0..15 (row group)
    const int tx = t & 15;          // 0..15 (col group)
    const int row0 = blockIdx.x * 64;
    const int lr = t >> 3;          // 0..31
    const int lk = (t & 7) << 2;    // 0..28

    float acc[4][16];
#pragma unroll
    for (int i = 0; i < 4; ++i)
#pragma unroll
        for (int j = 0; j < 16; ++j) acc[i][j] = 0.f;

    for (int k0 = 0; k0 < 512; k0 += 32) {
        __syncthreads();
#pragma unroll
        for (int rr = 0; rr < 2; ++rr) {
            int r = rr * 32 + lr;
            float4 v = *reinterpret_cast<const float4*>(&X[(size_t)(row0 + r) * 512 + k0 + lk]);
            *reinterpret_cast<float4*>(&Xs[r][lk]) = v;
        }
#pragma unroll
        for (int rr = 0; rr < 8; ++rr) {
            int r = rr * 32 + lr;
            float4 v = *reinterpret_cast<const float4*>(&P[(size_t)r * 512 + k0 + lk]);
            *reinterpret_cast<float4*>(&Ps[r][lk]) = v;
        }
        __syncthreads();
#pragma unroll 8
        for (int kk = 0; kk < 32; ++kk) {
            float a[4], b[16];
#pragma unroll
            for (int i = 0; i < 4; ++i) a[i] = Xs[i * 16 + ty][kk];
#pragma unroll
            for (int j = 0; j < 16; ++j) b[j] = Ps[j * 16 + tx][kk];
#pragma unroll
            for (int i = 0; i < 4; ++i)
#pragma unroll
                for (int j = 0; j < 16; ++j) acc[i][j] = fmaf(a[i], b[j], acc[i][j]);
        }
    }
#pragma unroll
    for (int i = 0; i < 4; ++i) {
        int r = row0 + i * 16 + ty;
#pragma unroll
        for (int j = 0; j < 16; ++j)
            dash[(size_t)r * 256 + j * 16 + tx] = acc[i][j] * SCALE_;
    }
}

// diag[row] = 0.5 * SCALE^2 * sum_d X[row,d]^2 ; one wave per row
__global__ __launch_bounds__(256) void diag_kernel(const float* __restrict__ X,
                                                   float* __restrict__ diag) {
    const int wave = threadIdx.x >> 6, lane = threadIdx.x & 63;
    const int row = blockIdx.x * 4 + wave;
    const float4* xr = reinterpret_cast<const float4*>(X + (size_t)row * 512);
    float4 a = xr[lane];
    float4 b = xr[64 + lane];
    float s = a.x * a.x + a.y * a.y + a.z * a.z + a.w * a.w +
              b.x * b.x + b.y * b.y + b.z * b.z + b.w * b.w;
#pragma unroll
    for (int off = 1; off < 64; off <<= 1) s += __shfl_xor(s, off);
    if (lane == 0) diag[row] = 0.5f * SCALE_ * SCALE_ * s;
}

// Qf = exp(dash - diag - rowmax)/16 + eps, in place; one wave per row
__global__ __launch_bounds__(256) void qf_finish(float* __restrict__ dash,
                                                 const float* __restrict__ diag) {
    const int wave = threadIdx.x >> 6, lane = threadIdx.x & 63;
    const int row = blockIdx.x * 4 + wave;
    float4* dr = reinterpret_cast<float4*>(dash + (size_t)row * 256);
    float4 v = dr[lane];
    float mx = fmaxf(fmaxf(v.x, v.y), fmaxf(v.z, v.w));
#pragma unroll
    for (int off = 1; off < 64; off <<= 1) mx = fmaxf(mx, __shfl_xor(mx, off));
    const float c = diag[row] + mx;
    v.x = expf(v.x - c) * RSQM_ + EPS_;
    v.y = expf(v.y - c) * RSQM_ + EPS_;
    v.z = expf(v.z - c) * RSQM_ + EPS_;
    v.w = expf(v.w - c) * RSQM_ + EPS_;
    dr[lane] = v;
}

// per-batch max of dashK, stage 1: 256 blocks, each reduces 32768 elems
__global__ __launch_bounds__(256) void kmax1(const float* __restrict__ dashK,
                                             float* __restrict__ part) {
    const size_t base = (size_t)blockIdx.x * 32768;
    float m = -1e30f;
    for (int i = threadIdx.x; i < 32768; i += 256) m = fmaxf(m, dashK[base + i]);
#pragma unroll
    for (int off = 1; off < 64; off <<= 1) m = fmaxf(m, __shfl_xor(m, off));
    __shared__ float red[4];
    if ((threadIdx.x & 63) == 0) red[threadIdx.x >> 6] = m;
    __syncthreads();
    if (threadIdx.x == 0)
        part[blockIdx.x] = fmaxf(fmaxf(red[0], red[1]), fmaxf(red[2], red[3]));
}

__global__ void kmax2(const float* __restrict__ part, float* __restrict__ bmax) {
    float m = part[blockIdx.x * 64 + threadIdx.x];
#pragma unroll
    for (int off = 1; off < 64; off <<= 1) m = fmaxf(m, __shfl_xor(m, off));
    if (threadIdx.x == 0) bmax[blockIdx.x] = m;
}

// Kf = exp(dash - diag - bmax[b])/16 + eps, in place
__global__ __launch_bounds__(256) void kf_finish(float* __restrict__ dash,
                                                 const float* __restrict__ diag,
                                                 const float* __restrict__ bmax) {
    const int wave = threadIdx.x >> 6, lane = threadIdx.x & 63;
    const int row = blockIdx.x * 4 + wave;
    const float c = diag[row] + bmax[row >> 13];
    float4* dr = reinterpret_cast<float4*>(dash + (size_t)row * 256);
    float4 v = dr[lane];
    v.x = expf(v.x - c) * RSQM_ + EPS_;
    v.y = expf(v.y - c) * RSQM_ + EPS_;
    v.z = expf(v.z - c) * RSQM_ + EPS_;
    v.w = expf(v.w - c) * RSQM_ + EPS_;
    dr[lane] = v;
}

// Ksum partials: 256 blocks, each sums 128 rows of Kf columns
__global__ __launch_bounds__(256) void ksum_part(const float* __restrict__ Kf,
                                                 float* __restrict__ kp) {
    const int b = blockIdx.x >> 6, ch = blockIdx.x & 63;
    size_t base = ((size_t)(b * 8192 + ch * 128)) * 256 + threadIdx.x;
    float s0 = 0, s1 = 0, s2 = 0, s3 = 0;
    for (int l = 0; l < 128; l += 4) {
        s0 += Kf[base + (size_t)l * 256];
        s1 += Kf[base + (size_t)(l + 1) * 256];
        s2 += Kf[base + (size_t)(l + 2) * 256];
        s3 += Kf[base + (size_t)(l + 3) * 256];
    }
    kp[(size_t)blockIdx.x * 256 + threadIdx.x] = (s0 + s1) + (s2 + s3);
}

__global__ void ksum_red(const float* __restrict__ kp, float* __restrict__ Ksum) {
    const int b = blockIdx.x, m = threadIdx.x;
    float s = 0;
    for (int ch = 0; ch < 64; ++ch) s += kp[((size_t)b * 64 + ch) * 256 + m];
    Ksum[b * 256 + m] = s;
}

// KV partial GEMM: C[m,d] += sum_l Kf[l,m]*V[l,d] over an L-chunk of 1024
// tile 64(m) x 128(d), 256 threads each 4x8
__global__ __launch_bounds__(256) void kv_part(const float* __restrict__ Kf,
                                               const float* __restrict__ V,
                                               float* __restrict__ kvp) {
    int bi = blockIdx.x;
    const int dt = bi & 3; bi >>= 2;
    const int mt = bi & 3; bi >>= 2;
    const int ch = bi & 7; bi >>= 3;
    const int b = bi;
    const int m0 = mt * 64, d0 = dt * 128;
    const size_t lbase = (size_t)b * 8192 + (size_t)ch * 1024;

    __shared__ float Ks[32][68];
    __shared__ float Vs[32][132];
    const int t = threadIdx.x;
    const int ty = t >> 4, tx = t & 15;
    float acc[4][8];
#pragma unroll
    for (int i = 0; i < 4; ++i)
#pragma unroll
        for (int j = 0; j < 8; ++j) acc[i][j] = 0.f;

    for (int l0 = 0; l0 < 1024; l0 += 32) {
        __syncthreads();
#pragma unroll
        for (int rr = 0; rr < 2; ++rr) {
            int l = rr * 16 + (t >> 4), m = (t & 15) << 2;
            *reinterpret_cast<float4*>(&Ks[l][m]) =
                *reinterpret_cast<const float4*>(&Kf[(lbase + l0 + l) * 256 + m0 + m]);
        }
#pragma unroll
        for (int rr = 0; rr < 4; ++rr) {
            int l = rr * 8 + (t >> 5), d = (t & 31) << 2;
            *reinterpret_cast<float4*>(&Vs[l][d]) =
                *reinterpret_cast<const float4*>(&V[(lbase + l0 + l) * 512 + d0 + d]);
        }
        __syncthreads();
#pragma unroll 8
        for (int l = 0; l < 32; ++l) {
            float a[4], bb[8];
#pragma unroll
            for (int i = 0; i < 4; ++i) a[i] = Ks[l][i * 16 + ty];
#pragma unroll
            for (int j = 0; j < 8; ++j) bb[j] = Vs[l][j * 16 + tx];
#pragma unroll
            for (int i = 0; i < 4; ++i)
#pragma unroll
                for (int j = 0; j < 8; ++j) acc[i][j] = fmaf(a[i], bb[j], acc[i][j]);
        }
    }
#pragma unroll
    for (int i = 0; i < 4; ++i) {
        size_t o = ((size_t)(ch * 4 + b) * 256 + m0 + i * 16 + ty) * 512 + d0;
#pragma unroll
        for (int j = 0; j < 8; ++j) kvp[o + j * 16 + tx] = acc[i][j];
    }
}

__global__ __launch_bounds__(256) void kv_reduce(const float* __restrict__ kvp,
                                                 float* __restrict__ KV) {
    const size_t i = (size_t)blockIdx.x * 256 + threadIdx.x;  // over B*M*D = 524288
    float s = 0;
#pragma unroll
    for (int c = 0; c < 8; ++c) s += kvp[(size_t)c * 524288 + i];
    KV[i] = s;
}

// Z[row] = 1/(dot(Qf[row,:], Ksum[b,:]) + eps); one wave per row
__global__ __launch_bounds__(256) void z_kernel(const float* __restrict__ Qf,
                                                const float* __restrict__ Ksum,
                                                float* __restrict__ Z) {
    const int wave = threadIdx.x >> 6, lane = threadIdx.x & 63;
    const int row = blockIdx.x * 4 + wave;
    const int b = row >> 13;
    float4 q = reinterpret_cast<const float4*>(Qf + (size_t)row * 256)[lane];
    float4 k = reinterpret_cast<const float4*>(Ksum + (size_t)b * 256)[lane];
    float s = q.x * k.x + q.y * k.y + q.z * k.z + q.w * k.w;
#pragma unroll
    for (int off = 1; off < 64; off <<= 1) s += __shfl_xor(s, off);
    if (lane == 0) Z[row] = 1.f / (s + EPS_);
}

// out[row,d] = Z[row] * sum_m Qf[row,m]*KV[b,m,d]; tile 64x128, K=M=256
__global__ __launch_bounds__(256) void out_gemm(const float* __restrict__ Qf,
                                                const float* __restrict__ KV,
                                                const float* __restrict__ Z,
                                                float* __restrict__ out) {
    const int dt = blockIdx.x & 3;
    const int rt = blockIdx.x >> 2;
    const int row0 = rt * 64, d0 = dt * 128;
    const int b = row0 >> 13;
    __shared__ float Qs[64][36];
    __shared__ float Ks2[32][132];
    const int t = threadIdx.x;
    const int ty = t >> 4, tx = t & 15;
    float acc[4][8];
#pragma unroll
    for (int i = 0; i < 4; ++i)
#pragma unroll
        for (int j = 0; j < 8; ++j) acc[i][j] = 0.f;

    for (int m0 = 0; m0 < 256; m0 += 32) {
        __syncthreads();
#pragma unroll
        for (int rr = 0; rr < 2; ++rr) {
            int r = rr * 32 + (t >> 3), mm = (t & 7) << 2;
            *reinterpret_cast<float4*>(&Qs[r][mm]) =
                *reinterpret_cast<const float4*>(&Qf[(size_t)(row0 + r) * 256 + m0 + mm]);
        }
#pragma unroll
        for (int rr = 0; rr < 4; ++rr) {
            int mm = rr * 8 + (t >> 5), dd = (t & 31) << 2;
            *reinterpret_cast<float4*>(&Ks2[mm][dd]) =
                *reinterpret_cast<const float4*>(&KV[((size_t)b * 256 + m0 + mm) * 512 + d0 + dd]);
        }
        __syncthreads();
#pragma unroll 8
        for (int mm = 0; mm < 32; ++mm) {
            float a[4], bb[8];
#pragma unroll
            for (int i = 0; i < 4; ++i) a[i] = Qs[i * 16 + ty][mm];
#pragma unroll
            for (int j = 0; j < 8; ++j) bb[j] = Ks2[mm][j * 16 + tx];
#pragma unroll
            for (int i = 0; i < 4; ++i)
#pragma unroll
                for (int j = 0; j < 8; ++j) acc[i][j] = fmaf(a[i], bb[j], acc[i][j]);
        }
    }
#pragma unroll
    for (int i = 0; i < 4; ++i) {
        const int r = row0 + i * 16 + ty;
        const float z = Z[r];
#pragma unroll
        for (int j = 0; j < 8; ++j)
            out[(size_t)r * 512 + d0 + j * 16 + tx] = acc[i][j] * z;
    }
}

extern "C" void kernel_launch(void* const* d_in, const int* in_sizes, int n_in,
                              void* d_out, int out_size, void* d_ws, size_t ws_size,
                              hipStream_t stream) {
    const float* Q = (const float*)d_in[0];
    const float* K = (const float*)d_in[1];
    const float* V = (const float*)d_in[2];
    const float* P = (const float*)d_in[3];
    float* out = (float*)d_out;
    char* ws = (char*)d_ws;

    float* dashQ = (float*)(ws + 0);           // 32 MB -> becomes Qf
    float* dashK = (float*)(ws + 33554432);    // 32 MB -> becomes Kf
    float* kvp   = (float*)(ws + 67108864);    // 16 MB
    float* KV    = (float*)(ws + 83886080);    // 2 MB
    float* diagQ = (float*)(ws + 85983232);    // 128 KB
    float* diagK = (float*)(ws + 86114304);    // 128 KB
    float* Zbuf  = (float*)(ws + 86245376);    // 128 KB
    float* ksump = (float*)(ws + 86376448);    // 64 KB
    float* Ksum  = (float*)(ws + 86441984);    // 4 KB
    float* kmaxp = (float*)(ws + 86446080);    // 1 KB
    float* bmax  = (float*)(ws + 86447104);    // 16 B

    dash_gemm<<<512, 256, 0, stream>>>(Q, P, dashQ);
    dash_gemm<<<512, 256, 0, stream>>>(K, P, dashK);
    diag_kernel<<<8192, 256, 0, stream>>>(Q, diagQ);
    diag_kernel<<<8192, 256, 0, stream>>>(K, diagK);
    qf_finish<<<8192, 256, 0, stream>>>(dashQ, diagQ);
    kmax1<<<256, 256, 0, stream>>>(dashK, kmaxp);
    kmax2<<<4, 64, 0, stream>>>(kmaxp, bmax);
    kf_finish<<<8192, 256, 0, stream>>>(dashK, diagK, bmax);
    ksum_part<<<256, 256, 0, stream>>>(dashK, ksump);
    ksum_red<<<4, 256, 0, stream>>>(ksump, Ksum);
    kv_part<<<512, 256, 0, stream>>>(dashK, V, kvp);
    kv_reduce<<<2048, 256, 0, stream>>>(kvp, KV);
    z_kernel<<<8192, 256, 0, stream>>>(dashQ, Ksum, Zbuf);
    out_gemm<<<2048, 256, 0, stream>>>(dashQ, KV, Zbuf, out);
}

// Round 2
// 325.565 us; speedup vs baseline: 1.8729x; 1.8729x over previous
//
#include <hip/hip_runtime.h>
#include <math.h>

typedef unsigned short u16;
typedef unsigned int u32;
typedef __attribute__((ext_vector_type(8))) short bf16x8;
typedef __attribute__((ext_vector_type(4))) float f32x4;

#define SCALE_ 0.21022410381342864f   // 512^{-1/4}
#define EPS_ 1e-6f
#define RSQM_ 0.0625f                 // 1/sqrt(256)

__device__ __forceinline__ u16 bfhi(float x) {
    u32 u = __float_as_uint(x);
    return (u16)((u + 0x7FFFu + ((u >> 16) & 1u)) >> 16);  // RNE bf16
}
__device__ __forceinline__ float bf2f(u16 h) {
    return __uint_as_float(((u32)h) << 16);
}
__device__ __forceinline__ void split2(float x, u16& h, u16& l) {
    h = bfhi(x);
    l = bfhi(x - bf2f(h));
}

#define GLDS16(gsrc, ldst) \
    __builtin_amdgcn_global_load_lds((__attribute__((address_space(1))) void*)(gsrc), \
                                     (__attribute__((address_space(3))) void*)(ldst), 16, 0, 0)

// ---------------------------------------------------------------------------
// split X row-major: xs = SCALE*x -> hi/lo bf16 [32768][512]; diag = 0.5*sum(xs^2)
// ---------------------------------------------------------------------------
__global__ __launch_bounds__(256) void split_rows(const float* __restrict__ X,
        u16* __restrict__ H, u16* __restrict__ L, float* __restrict__ diag) {
    const int wid = threadIdx.x >> 6, lane = threadIdx.x & 63;
    const int row = blockIdx.x * 4 + wid;
    const float4* xr = reinterpret_cast<const float4*>(X + (size_t)row * 512);
    float4 a = xr[lane], b = xr[64 + lane];
    float xs[8] = {a.x, a.y, a.z, a.w, b.x, b.y, b.z, b.w};
    float ss = 0.f;
    u32 hw[4], lw[4];
#pragma unroll
    for (int i = 0; i < 8; ++i) { xs[i] *= SCALE_; ss = fmaf(xs[i], xs[i], ss); }
#pragma unroll
    for (int i = 0; i < 4; ++i) {
        u16 h0, l0, h1, l1;
        split2(xs[2 * i], h0, l0); split2(xs[2 * i + 1], h1, l1);
        hw[i] = (u32)h0 | ((u32)h1 << 16);
        lw[i] = (u32)l0 | ((u32)l1 << 16);
    }
    size_t o1 = (size_t)row * 512 + lane * 4, o2 = o1 + 256;
    *reinterpret_cast<uint2*>(&H[o1]) = make_uint2(hw[0], hw[1]);
    *reinterpret_cast<uint2*>(&H[o2]) = make_uint2(hw[2], hw[3]);
    *reinterpret_cast<uint2*>(&L[o1]) = make_uint2(lw[0], lw[1]);
    *reinterpret_cast<uint2*>(&L[o2]) = make_uint2(lw[2], lw[3]);
#pragma unroll
    for (int off = 1; off < 64; off <<= 1) ss += __shfl_xor(ss, off);
    if (lane == 0) diag[row] = 0.5f * ss;
}

__global__ __launch_bounds__(256) void split_p(const float* __restrict__ P,
        u16* __restrict__ Ph, u16* __restrict__ Pl) {
    int i = blockIdx.x * 256 + threadIdx.x;
    u16 h, l; split2(P[i], h, l);
    Ph[i] = h; Pl[i] = l;
}

// ---------------------------------------------------------------------------
// dash GEMM: (32768x512)x(256x512)^T via split-bf16 MFMA. Tile 128x256 (full M),
// 512 threads (8 waves 2x4). FUSED=1: rowmax+exp+split epilogue -> Qf hi/lo.
// FUSED=0: write fp32 dash (K path needs global batch max first).
// ---------------------------------------------------------------------------
template<int FUSED>
__global__ __launch_bounds__(512) void dash_mfma(
        const u16* __restrict__ Ah_g, const u16* __restrict__ Al_g,
        const u16* __restrict__ Bh_g, const u16* __restrict__ Bl_g,
        const float* __restrict__ diag, float* __restrict__ dashOut,
        u16* __restrict__ Fh, u16* __restrict__ Fl) {
    __shared__ __align__(16) u16 Ah[128 * 32], Al[128 * 32];
    __shared__ __align__(16) u16 Bh[256 * 32], Bl[256 * 32];
    __shared__ float rmax[128][4];
    const int t = threadIdx.x, lane = t & 63;
    const int wid = t >> 6, wr = wid >> 2, wc = wid & 3;
    const int row0 = blockIdx.x * 128;
    const int l15 = lane & 15, l4 = lane >> 4;
    const int sr = t >> 2, kc = (t & 3) * 8;
    const int wb = (t >> 6) * 512;   // wave-uniform LDS elem base

    f32x4 acc[4][4];
#pragma unroll
    for (int i = 0; i < 4; ++i)
#pragma unroll
        for (int j = 0; j < 4; ++j) acc[i][j] = (f32x4){0.f, 0.f, 0.f, 0.f};

    for (int k0 = 0; k0 < 512; k0 += 32) {
        __syncthreads();
        {
            const size_t ga = (size_t)(row0 + sr) * 512 + k0 + kc;
            GLDS16(Ah_g + ga, Ah + wb);
            GLDS16(Al_g + ga, Al + wb);
            const size_t gb0 = (size_t)sr * 512 + k0 + kc;
            GLDS16(Bh_g + gb0, Bh + wb);
            GLDS16(Bl_g + gb0, Bl + wb);
            const size_t gb1 = (size_t)(128 + sr) * 512 + k0 + kc;
            GLDS16(Bh_g + gb1, Bh + 4096 + wb);
            GLDS16(Bl_g + gb1, Bl + 4096 + wb);
        }
        __syncthreads();
        bf16x8 a_h[4], a_l[4], b_h[4], b_l[4];
        const int koff = l4 * 8;
#pragma unroll
        for (int mf = 0; mf < 4; ++mf) {
            int r = (wr * 64 + mf * 16 + l15) * 32 + koff;
            a_h[mf] = *reinterpret_cast<const bf16x8*>(&Ah[r]);
            a_l[mf] = *reinterpret_cast<const bf16x8*>(&Al[r]);
        }
#pragma unroll
        for (int nf = 0; nf < 4; ++nf) {
            int r = (wc * 64 + nf * 16 + l15) * 32 + koff;
            b_h[nf] = *reinterpret_cast<const bf16x8*>(&Bh[r]);
            b_l[nf] = *reinterpret_cast<const bf16x8*>(&Bl[r]);
        }
#pragma unroll
        for (int mf = 0; mf < 4; ++mf)
#pragma unroll
            for (int nf = 0; nf < 4; ++nf) {
                acc[mf][nf] = __builtin_amdgcn_mfma_f32_16x16x32_bf16(a_h[mf], b_h[nf], acc[mf][nf], 0, 0, 0);
                acc[mf][nf] = __builtin_amdgcn_mfma_f32_16x16x32_bf16(a_h[mf], b_l[nf], acc[mf][nf], 0, 0, 0);
                acc[mf][nf] = __builtin_amdgcn_mfma_f32_16x16x32_bf16(a_l[mf], b_h[nf], acc[mf][nf], 0, 0, 0);
            }
    }

    if (FUSED) {
        float rm[4][4];
#pragma unroll
        for (int mf = 0; mf < 4; ++mf)
#pragma unroll
            for (int r = 0; r < 4; ++r) {
                float v = fmaxf(fmaxf(acc[mf][0][r], acc[mf][1][r]),
                                fmaxf(acc[mf][2][r], acc[mf][3][r]));
#pragma unroll
                for (int off = 1; off < 16; off <<= 1) v = fmaxf(v, __shfl_xor(v, off));
                rm[mf][r] = v;
            }
        if (l15 == 0) {
#pragma unroll
            for (int mf = 0; mf < 4; ++mf)
#pragma unroll
                for (int r = 0; r < 4; ++r)
                    rmax[wr * 64 + mf * 16 + l4 * 4 + r][wc] = rm[mf][r];
        }
        __syncthreads();
#pragma unroll
        for (int mf = 0; mf < 4; ++mf)
#pragma unroll
            for (int r = 0; r < 4; ++r) {
                const int rl = wr * 64 + mf * 16 + l4 * 4 + r;
                float m4 = fmaxf(fmaxf(rmax[rl][0], rmax[rl][1]),
                                 fmaxf(rmax[rl][2], rmax[rl][3]));
                const float c = diag[row0 + rl] + m4;
#pragma unroll
                for (int nf = 0; nf < 4; ++nf) {
                    float f = expf(acc[mf][nf][r] - c) * RSQM_ + EPS_;
                    u16 h, l; split2(f, h, l);
                    size_t o = (size_t)(row0 + rl) * 256 + wc * 64 + nf * 16 + l15;
                    Fh[o] = h; Fl[o] = l;
                }
            }
    } else {
#pragma unroll
        for (int mf = 0; mf < 4; ++mf)
#pragma unroll
            for (int r = 0; r < 4; ++r) {
                const int rl = wr * 64 + mf * 16 + l4 * 4 + r;
#pragma unroll
                for (int nf = 0; nf < 4; ++nf)
                    dashOut[(size_t)(row0 + rl) * 256 + wc * 64 + nf * 16 + l15] = acc[mf][nf][r];
            }
    }
}

// per-batch max of dashK
__global__ __launch_bounds__(256) void kmax1(const float* __restrict__ dashK,
                                             float* __restrict__ part) {
    const size_t base = (size_t)blockIdx.x * 32768;
    float m = -1e30f;
    for (int i = threadIdx.x; i < 32768; i += 256) m = fmaxf(m, dashK[base + i]);
#pragma unroll
    for (int off = 1; off < 64; off <<= 1) m = fmaxf(m, __shfl_xor(m, off));
    __shared__ float red[4];
    if ((threadIdx.x & 63) == 0) red[threadIdx.x >> 6] = m;
    __syncthreads();
    if (threadIdx.x == 0)
        part[blockIdx.x] = fmaxf(fmaxf(red[0], red[1]), fmaxf(red[2], red[3]));
}

__global__ void kmax2(const float* __restrict__ part, float* __restrict__ bmax) {
    float m = part[blockIdx.x * 64 + threadIdx.x];
#pragma unroll
    for (int off = 1; off < 64; off <<= 1) m = fmaxf(m, __shfl_xor(m, off));
    if (threadIdx.x == 0) bmax[blockIdx.x] = m;
}

// ---------------------------------------------------------------------------
// Kf finish + transpose: exp(dash - diag - bmax)/16 + eps -> KfT[b][m][l] hi/lo
// tile 64(l) x 64(m), LDS transpose
// ---------------------------------------------------------------------------
__global__ __launch_bounds__(256) void kfinish_t(const float* __restrict__ dash,
        const float* __restrict__ diag, const float* __restrict__ bmax,
        u16* __restrict__ KfTh, u16* __restrict__ KfTl) {
    const int mt = blockIdx.x & 3, lt = blockIdx.x >> 2;
    const int l0 = lt * 64, m0 = mt * 64;
    const int b = l0 >> 13;
    __shared__ u16 Th[64][72], Tl[64][72];
    const int t = threadIdx.x;
    const int lrow = t >> 2, c0 = (t & 3) * 16;
    const float c = diag[l0 + lrow] + bmax[b];
#pragma unroll
    for (int ii = 0; ii < 4; ++ii) {
        float4 v = *reinterpret_cast<const float4*>(&dash[(size_t)(l0 + lrow) * 256 + m0 + c0 + ii * 4]);
        float e[4] = {expf(v.x - c) * RSQM_ + EPS_, expf(v.y - c) * RSQM_ + EPS_,
                      expf(v.z - c) * RSQM_ + EPS_, expf(v.w - c) * RSQM_ + EPS_};
#pragma unroll
        for (int j = 0; j < 4; ++j) {
            u16 h, l; split2(e[j], h, l);
            Th[lrow][c0 + ii * 4 + j] = h;
            Tl[lrow][c0 + ii * 4 + j] = l;
        }
    }
    __syncthreads();
    const int mloc = t >> 2, lc = (t & 3) * 16;
    size_t ob = ((size_t)(b * 256 + m0 + mloc)) * 8192 + (l0 & 8191) + lc;
    u32 wh[8], wl[8];
#pragma unroll
    for (int j = 0; j < 8; ++j) {
        wh[j] = (u32)Th[lc + 2 * j][mloc] | ((u32)Th[lc + 2 * j + 1][mloc] << 16);
        wl[j] = (u32)Tl[lc + 2 * j][mloc] | ((u32)Tl[lc + 2 * j + 1][mloc] << 16);
    }
    reinterpret_cast<uint4*>(&KfTh[ob])[0] = make_uint4(wh[0], wh[1], wh[2], wh[3]);
    reinterpret_cast<uint4*>(&KfTh[ob])[1] = make_uint4(wh[4], wh[5], wh[6], wh[7]);
    reinterpret_cast<uint4*>(&KfTl[ob])[0] = make_uint4(wl[0], wl[1], wl[2], wl[3]);
    reinterpret_cast<uint4*>(&KfTl[ob])[1] = make_uint4(wl[4], wl[5], wl[6], wl[7]);
}

// V split + transpose: Vt[b][d][l] hi/lo; tile 64(l) x 64(d)
__global__ __launch_bounds__(256) void split_vt(const float* __restrict__ V,
        u16* __restrict__ Vth, u16* __restrict__ Vtl) {
    const int dt = blockIdx.x & 7, lt = blockIdx.x >> 3;
    const int lg = lt * 64;
    const int b = lg >> 13;
    const int d0 = dt * 64;
    __shared__ u16 Th[64][72], Tl[64][72];
    const int t = threadIdx.x;
    const int lrow = t >> 2, c0 = (t & 3) * 16;
#pragma unroll
    for (int ii = 0; ii < 4; ++ii) {
        float4 v = *reinterpret_cast<const float4*>(&V[(size_t)(lg + lrow) * 512 + d0 + c0 + ii * 4]);
        float e[4] = {v.x, v.y, v.z, v.w};
#pragma unroll
        for (int j = 0; j < 4; ++j) {
            u16 h, l; split2(e[j], h, l);
            Th[lrow][c0 + ii * 4 + j] = h;
            Tl[lrow][c0 + ii * 4 + j] = l;
        }
    }
    __syncthreads();
    const int dloc = t >> 2, lc = (t & 3) * 16;
    size_t ob = ((size_t)(b * 512 + d0 + dloc)) * 8192 + (lg & 8191) + lc;
    u32 wh[8], wl[8];
#pragma unroll
    for (int j = 0; j < 8; ++j) {
        wh[j] = (u32)Th[lc + 2 * j][dloc] | ((u32)Th[lc + 2 * j + 1][dloc] << 16);
        wl[j] = (u32)Tl[lc + 2 * j][dloc] | ((u32)Tl[lc + 2 * j + 1][dloc] << 16);
    }
    reinterpret_cast<uint4*>(&Vth[ob])[0] = make_uint4(wh[0], wh[1], wh[2], wh[3]);
    reinterpret_cast<uint4*>(&Vth[ob])[1] = make_uint4(wh[4], wh[5], wh[6], wh[7]);
    reinterpret_cast<uint4*>(&Vtl[ob])[0] = make_uint4(wl[0], wl[1], wl[2], wl[3]);
    reinterpret_cast<uint4*>(&Vtl[ob])[1] = make_uint4(wl[4], wl[5], wl[6], wl[7]);
}

// Ksum[b][m] = sum_l Kf ; one wave per (b,m) row of KfT
__global__ __launch_bounds__(256) void ksum_t(const u16* __restrict__ KfTh,
        const u16* __restrict__ KfTl, float* __restrict__ Ksum) {
    const int g = blockIdx.x * 4 + (threadIdx.x >> 6), lane = threadIdx.x & 63;
    const u16* rh = KfTh + (size_t)g * 8192;
    const u16* rl = KfTl + (size_t)g * 8192;
    float s = 0.f;
    for (int it = 0; it < 16; ++it) {
        int idx = it * 512 + lane * 8;
        uint4 uh = *reinterpret_cast<const uint4*>(&rh[idx]);
        uint4 ul = *reinterpret_cast<const uint4*>(&rl[idx]);
        u32 w[8] = {uh.x, uh.y, uh.z, uh.w, ul.x, ul.y, ul.z, ul.w};
#pragma unroll
        for (int j = 0; j < 8; ++j)
            s += bf2f((u16)(w[j] & 0xffff)) + bf2f((u16)(w[j] >> 16));
    }
#pragma unroll
    for (int off = 1; off < 64; off <<= 1) s += __shfl_xor(s, off);
    if (lane == 0) Ksum[g] = s;
}

// ---------------------------------------------------------------------------
// KV split-K GEMM: kvp[ch][b][m][d] partial over 1024-l chunk. Tile 128x128,
// 256 threads (2x2 waves), split-bf16 MFMA.
// ---------------------------------------------------------------------------
__global__ __launch_bounds__(256) void kv_mfma(
        const u16* __restrict__ KfTh, const u16* __restrict__ KfTl,
        const u16* __restrict__ Vth, const u16* __restrict__ Vtl,
        float* __restrict__ kvp) {
    int bi = blockIdx.x;
    const int dt = bi & 3; bi >>= 2;
    const int mt = bi & 1; bi >>= 1;
    const int ch = bi & 7; bi >>= 3;
    const int b = bi;
    const u16* Ag_h = KfTh + ((size_t)(b * 256 + mt * 128)) * 8192 + ch * 1024;
    const u16* Ag_l = KfTl + ((size_t)(b * 256 + mt * 128)) * 8192 + ch * 1024;
    const u16* Bg_h = Vth + ((size_t)(b * 512 + dt * 128)) * 8192 + ch * 1024;
    const u16* Bg_l = Vtl + ((size_t)(b * 512 + dt * 128)) * 8192 + ch * 1024;
    __shared__ __align__(16) u16 Ah[128 * 32], Al[128 * 32], Bh[128 * 32], Bl[128 * 32];
    const int t = threadIdx.x, lane = t & 63;
    const int wid = t >> 6, wr = wid >> 1, wc = wid & 1;
    const int l15 = lane & 15, l4 = lane >> 4;
    const int sr = t >> 2, kc = (t & 3) * 8;
    f32x4 acc[4][4];
#pragma unroll
    for (int i = 0; i < 4; ++i)
#pragma unroll
        for (int j = 0; j < 4; ++j) acc[i][j] = (f32x4){0.f, 0.f, 0.f, 0.f};

    for (int k0 = 0; k0 < 1024; k0 += 32) {
        __syncthreads();
#pragma unroll
        for (int it = 0; it < 2; ++it) {
            const size_t g = (size_t)(it * 64 + sr) * 8192 + k0 + kc;
            const int dst = it * 2048 + (t >> 6) * 512;
            GLDS16(Ag_h + g, Ah + dst);
            GLDS16(Ag_l + g, Al + dst);
            GLDS16(Bg_h + g, Bh + dst);
            GLDS16(Bg_l + g, Bl + dst);
        }
        __syncthreads();
        bf16x8 a_h[4], a_l[4], b_h[4], b_l[4];
        const int koff = l4 * 8;
#pragma unroll
        for (int mf = 0; mf < 4; ++mf) {
            int r = (wr * 64 + mf * 16 + l15) * 32 + koff;
            a_h[mf] = *reinterpret_cast<const bf16x8*>(&Ah[r]);
            a_l[mf] = *reinterpret_cast<const bf16x8*>(&Al[r]);
        }
#pragma unroll
        for (int nf = 0; nf < 4; ++nf) {
            int r = (wc * 64 + nf * 16 + l15) * 32 + koff;
            b_h[nf] = *reinterpret_cast<const bf16x8*>(&Bh[r]);
            b_l[nf] = *reinterpret_cast<const bf16x8*>(&Bl[r]);
        }
#pragma unroll
        for (int mf = 0; mf < 4; ++mf)
#pragma unroll
            for (int nf = 0; nf < 4; ++nf) {
                acc[mf][nf] = __builtin_amdgcn_mfma_f32_16x16x32_bf16(a_h[mf], b_h[nf], acc[mf][nf], 0, 0, 0);
                acc[mf][nf] = __builtin_amdgcn_mfma_f32_16x16x32_bf16(a_h[mf], b_l[nf], acc[mf][nf], 0, 0, 0);
                acc[mf][nf] = __builtin_amdgcn_mfma_f32_16x16x32_bf16(a_l[mf], b_h[nf], acc[mf][nf], 0, 0, 0);
            }
    }
    const int mbase = mt * 128 + wr * 64;
    const int dbase = dt * 128 + wc * 64;
#pragma unroll
    for (int mf = 0; mf < 4; ++mf)
#pragma unroll
        for (int r = 0; r < 4; ++r) {
            size_t o = ((size_t)(ch * 4 + b) * 256 + mbase + mf * 16 + l4 * 4 + r) * 512 + dbase;
#pragma unroll
            for (int nf = 0; nf < 4; ++nf)
                kvp[o + nf * 16 + l15] = acc[mf][nf][r];
        }
}

// reduce 8 chunks + split + transpose -> KVt[b][d][m] hi/lo; tile 64(m) x 64(d)
__global__ __launch_bounds__(256) void kv_reduce_t(const float* __restrict__ kvp,
        u16* __restrict__ KVth, u16* __restrict__ KVtl) {
    const int dt = blockIdx.x & 7, mt = (blockIdx.x >> 3) & 3, b = blockIdx.x >> 5;
    const int m0 = mt * 64, d0 = dt * 64;
    __shared__ u16 Th[64][72], Tl[64][72];
    const int t = threadIdx.x, mloc = t >> 2, c0 = (t & 3) * 16;
    float s[16];
#pragma unroll
    for (int j = 0; j < 16; ++j) s[j] = 0.f;
#pragma unroll
    for (int c = 0; c < 8; ++c) {
        size_t base = ((size_t)(c * 4 + b) * 256 + m0 + mloc) * 512 + d0 + c0;
#pragma unroll
        for (int ii = 0; ii < 4; ++ii) {
            float4 v = *reinterpret_cast<const float4*>(&kvp[base + ii * 4]);
            s[ii * 4 + 0] += v.x; s[ii * 4 + 1] += v.y;
            s[ii * 4 + 2] += v.z; s[ii * 4 + 3] += v.w;
        }
    }
#pragma unroll
    for (int j = 0; j < 16; ++j) {
        u16 h, l; split2(s[j], h, l);
        Th[mloc][c0 + j] = h;
        Tl[mloc][c0 + j] = l;
    }
    __syncthreads();
    const int dloc = t >> 2, mc = (t & 3) * 16;
    size_t ob = ((size_t)(b * 512 + d0 + dloc)) * 256 + m0 + mc;
    u32 wh[8], wl[8];
#pragma unroll
    for (int j = 0; j < 8; ++j) {
        wh[j] = (u32)Th[mc + 2 * j][dloc] | ((u32)Th[mc + 2 * j + 1][dloc] << 16);
        wl[j] = (u32)Tl[mc + 2 * j][dloc] | ((u32)Tl[mc + 2 * j + 1][dloc] << 16);
    }
    reinterpret_cast<uint4*>(&KVth[ob])[0] = make_uint4(wh[0], wh[1], wh[2], wh[3]);
    reinterpret_cast<uint4*>(&KVth[ob])[1] = make_uint4(wh[4], wh[5], wh[6], wh[7]);
    reinterpret_cast<uint4*>(&KVtl[ob])[0] = make_uint4(wl[0], wl[1], wl[2], wl[3]);
    reinterpret_cast<uint4*>(&KVtl[ob])[1] = make_uint4(wl[4], wl[5], wl[6], wl[7]);
}

// Z[row] = 1/(dot(Qf, Ksum[b]) + eps)
__global__ __launch_bounds__(256) void z_bf16(const u16* __restrict__ Qfh,
        const u16* __restrict__ Qfl, const float* __restrict__ Ksum,
        float* __restrict__ Z) {
    const int wid = threadIdx.x >> 6, lane = threadIdx.x & 63;
    const int row = blockIdx.x * 4 + wid;
    const int b = row >> 13;
    uint2 uh = *reinterpret_cast<const uint2*>(&Qfh[(size_t)row * 256 + lane * 4]);
    uint2 ul = *reinterpret_cast<const uint2*>(&Qfl[(size_t)row * 256 + lane * 4]);
    float4 ks = *reinterpret_cast<const float4*>(&Ksum[b * 256 + lane * 4]);
    float q0 = bf2f((u16)(uh.x & 0xffff)) + bf2f((u16)(ul.x & 0xffff));
    float q1 = bf2f((u16)(uh.x >> 16)) + bf2f((u16)(ul.x >> 16));
    float q2 = bf2f((u16)(uh.y & 0xffff)) + bf2f((u16)(ul.y & 0xffff));
    float q3 = bf2f((u16)(uh.y >> 16)) + bf2f((u16)(ul.y >> 16));
    float s = q0 * ks.x + q1 * ks.y + q2 * ks.z + q3 * ks.w;
#pragma unroll
    for (int off = 1; off < 64; off <<= 1) s += __shfl_xor(s, off);
    if (lane == 0) Z[row] = 1.f / (s + EPS_);
}

// ---------------------------------------------------------------------------
// out GEMM: out[row][d] = Z[row]*sum_m Qf[row][m]*KVt[d][m]; tile 128x128, K=256
// ---------------------------------------------------------------------------
__global__ __launch_bounds__(256) void out_mfma(
        const u16* __restrict__ Qfh, const u16* __restrict__ Qfl,
        const u16* __restrict__ KVth, const u16* __restrict__ KVtl,
        const float* __restrict__ Z, float* __restrict__ out) {
    const int dt = blockIdx.x & 3, rt = blockIdx.x >> 2;
    const int row0 = rt * 128;
    const int b = row0 >> 13;
    const u16* Ag_h = Qfh + (size_t)row0 * 256;
    const u16* Ag_l = Qfl + (size_t)row0 * 256;
    const u16* Bg_h = KVth + ((size_t)(b * 512 + dt * 128)) * 256;
    const u16* Bg_l = KVtl + ((size_t)(b * 512 + dt * 128)) * 256;
    __shared__ __align__(16) u16 Ah[128 * 32], Al[128 * 32], Bh[128 * 32], Bl[128 * 32];
    const int t = threadIdx.x, lane = t & 63;
    const int wid = t >> 6, wr = wid >> 1, wc = wid & 1;
    const int l15 = lane & 15, l4 = lane >> 4;
    const int sr = t >> 2, kc = (t & 3) * 8;
    f32x4 acc[4][4];
#pragma unroll
    for (int i = 0; i < 4; ++i)
#pragma unroll
        for (int j = 0; j < 4; ++j) acc[i][j] = (f32x4){0.f, 0.f, 0.f, 0.f};

    for (int k0 = 0; k0 < 256; k0 += 32) {
        __syncthreads();
#pragma unroll
        for (int it = 0; it < 2; ++it) {
            const size_t g = (size_t)(it * 64 + sr) * 256 + k0 + kc;
            const int dst = it * 2048 + (t >> 6) * 512;
            GLDS16(Ag_h + g, Ah + dst);
            GLDS16(Ag_l + g, Al + dst);
            GLDS16(Bg_h + g, Bh + dst);
            GLDS16(Bg_l + g, Bl + dst);
        }
        __syncthreads();
        bf16x8 a_h[4], a_l[4], b_h[4], b_l[4];
        const int koff = l4 * 8;
#pragma unroll
        for (int mf = 0; mf < 4; ++mf) {
            int r = (wr * 64 + mf * 16 + l15) * 32 + koff;
            a_h[mf] = *reinterpret_cast<const bf16x8*>(&Ah[r]);
            a_l[mf] = *reinterpret_cast<const bf16x8*>(&Al[r]);
        }
#pragma unroll
        for (int nf = 0; nf < 4; ++nf) {
            int r = (wc * 64 + nf * 16 + l15) * 32 + koff;
            b_h[nf] = *reinterpret_cast<const bf16x8*>(&Bh[r]);
            b_l[nf] = *reinterpret_cast<const bf16x8*>(&Bl[r]);
        }
#pragma unroll
        for (int mf = 0; mf < 4; ++mf)
#pragma unroll
            for (int nf = 0; nf < 4; ++nf) {
                acc[mf][nf] = __builtin_amdgcn_mfma_f32_16x16x32_bf16(a_h[mf], b_h[nf], acc[mf][nf], 0, 0, 0);
                acc[mf][nf] = __builtin_amdgcn_mfma_f32_16x16x32_bf16(a_h[mf], b_l[nf], acc[mf][nf], 0, 0, 0);
                acc[mf][nf] = __builtin_amdgcn_mfma_f32_16x16x32_bf16(a_l[mf], b_h[nf], acc[mf][nf], 0, 0, 0);
            }
    }
#pragma unroll
    for (int mf = 0; mf < 4; ++mf)
#pragma unroll
        for (int r = 0; r < 4; ++r) {
            const int row = row0 + wr * 64 + mf * 16 + l4 * 4 + r;
            const float z = Z[row];
#pragma unroll
            for (int nf = 0; nf < 4; ++nf)
                out[(size_t)row * 512 + dt * 128 + wc * 64 + nf * 16 + l15] = acc[mf][nf][r] * z;
        }
}

extern "C" void kernel_launch(void* const* d_in, const int* in_sizes, int n_in,
                              void* d_out, int out_size, void* d_ws, size_t ws_size,
                              hipStream_t stream) {
    const float* Q = (const float*)d_in[0];
    const float* K = (const float*)d_in[1];
    const float* V = (const float*)d_in[2];
    const float* P = (const float*)d_in[3];
    float* out = (float*)d_out;
    char* ws = (char*)d_ws;

    u16* R0H   = (u16*)(ws + 0);            // 32 MiB: Q/K input splits, later Vth
    u16* R0L   = (u16*)(ws + 33554432);     // 32 MiB: lo parts, later Vtl
    u16* QFH   = (u16*)(ws + 67108864);     // 16 MiB
    u16* QFL   = (u16*)(ws + 83886080);     // 16 MiB
    float* dashK = (float*)(ws + 100663296);// 32 MiB, later kvp(16)+KVt
    float* kvp   = (float*)(ws + 100663296);
    u16* KVTH  = (u16*)(ws + 117440512);    // 1 MiB
    u16* KVTL  = (u16*)(ws + 118489088);    // 1 MiB
    u16* KFTH  = (u16*)(ws + 134217728);    // 16 MiB
    u16* KFTL  = (u16*)(ws + 150994944);    // 16 MiB
    u16* PH    = (u16*)(ws + 167772160);    // 256 KiB
    u16* PL    = (u16*)(ws + 168034304);    // 256 KiB
    float* diagQ = (float*)(ws + 168296448);// 128 KiB
    float* diagK = (float*)(ws + 168427520);// 128 KiB
    float* Zbuf  = (float*)(ws + 168558592);// 128 KiB
    float* Ksum  = (float*)(ws + 168689664);// 4 KiB
    float* kmaxp = (float*)(ws + 168693760);// 1 KiB
    float* bmax  = (float*)(ws + 168694784);// 16 B

    split_p<<<512, 256, 0, stream>>>(P, PH, PL);
    split_rows<<<8192, 256, 0, stream>>>(Q, R0H, R0L, diagQ);
    dash_mfma<1><<<256, 512, 0, stream>>>(R0H, R0L, PH, PL, diagQ, nullptr, QFH, QFL);
    split_rows<<<8192, 256, 0, stream>>>(K, R0H, R0L, diagK);
    dash_mfma<0><<<256, 512, 0, stream>>>(R0H, R0L, PH, PL, diagK, dashK, nullptr, nullptr);
    kmax1<<<256, 256, 0, stream>>>(dashK, kmaxp);
    kmax2<<<4, 64, 0, stream>>>(kmaxp, bmax);
    kfinish_t<<<2048, 256, 0, stream>>>(dashK, diagK, bmax, KFTH, KFTL);
    ksum_t<<<256, 256, 0, stream>>>(KFTH, KFTL, Ksum);
    split_vt<<<4096, 256, 0, stream>>>(V, R0H, R0L);
    kv_mfma<<<256, 256, 0, stream>>>(KFTH, KFTL, R0H, R0L, kvp);
    kv_reduce_t<<<128, 256, 0, stream>>>(kvp, KVTH, KVTL);
    z_bf16<<<8192, 256, 0, stream>>>(QFH, QFL, Ksum, Zbuf);
    out_mfma<<<1024, 256, 0, stream>>>(QFH, QFL, KVTH, KVTL, Zbuf, out);
}

// Round 3
// 201.076 us; speedup vs baseline: 3.0325x; 1.6191x over previous
//
#include <hip/hip_runtime.h>
#include <math.h>

typedef unsigned short u16;
typedef unsigned int u32;
typedef __attribute__((ext_vector_type(8))) short bf16x8;
typedef __attribute__((ext_vector_type(4))) float f32x4;

#define SCALE_ 0.21022410381342864f   // 512^{-1/4}
#define EPS_ 1e-6f
#define RSQM_ 0.0625f                 // 1/sqrt(256)
#define L_ 8192

__device__ __forceinline__ u16 bfhi(float x) {
    u32 u = __float_as_uint(x);
    return (u16)((u + 0x7FFFu + ((u >> 16) & 1u)) >> 16);  // RNE bf16
}
__device__ __forceinline__ float bf2f(u16 h) {
    return __uint_as_float(((u32)h) << 16);
}
__device__ __forceinline__ void split2(float x, u16& h, u16& l) {
    h = bfhi(x);
    l = bfhi(x - bf2f(h));
}
__device__ __forceinline__ u32 okey(float x) {   // order-preserving float->u32
    u32 b = __float_as_uint(x);
    return (b & 0x80000000u) ? ~b : (b | 0x80000000u);
}
__device__ __forceinline__ float odec(u32 k) {
    return (k & 0x80000000u) ? __uint_as_float(k & 0x7fffffffu) : __uint_as_float(~k);
}

#define GLDS16(gsrc, ldst) \
    __builtin_amdgcn_global_load_lds((__attribute__((address_space(1))) void*)(gsrc), \
                                     (__attribute__((address_space(3))) void*)(ldst), 16, 0, 0)

__global__ void init_k(u32* __restrict__ bmax) {
    if (threadIdx.x < 4) bmax[threadIdx.x] = 0u;
}

__global__ __launch_bounds__(256) void split_p(const float* __restrict__ P,
        u16* __restrict__ Ph, u16* __restrict__ Pl) {
    int i = blockIdx.x * 256 + threadIdx.x;
    u16 h, l; split2(P[i], h, l);
    Ph[i] = h; Pl[i] = l;
}

// ---------------------------------------------------------------------------
// Fused dash GEMM: reads fp32 X rows, splits to hi/lo in-kernel (A), P from
// pre-split hi/lo (B, GLDS16). diag computed inline. Tile 128x256, 512 thr.
// QPATH=1: rowmax+exp -> Qf bf16.  QPATH=0: exp(dash-diag) -> KfE bf16 + atomicMax bmax.
// ---------------------------------------------------------------------------
template<int QPATH>
__global__ __launch_bounds__(512) void dash_fused(
        const float* __restrict__ X,
        const u16* __restrict__ Bh_g, const u16* __restrict__ Bl_g,
        u16* __restrict__ F, u32* __restrict__ bmax) {
    __shared__ __align__(16) u16 Ah[128 * 32], Al[128 * 32];
    __shared__ __align__(16) u16 Bh[256 * 32], Bl[256 * 32];
    __shared__ float rmax[128][4];
    __shared__ float diag_s[128];
    __shared__ float wmax[8];
    const int t = threadIdx.x, lane = t & 63;
    const int wid = t >> 6, wr = wid >> 2, wc = wid & 3;
    const int row0 = blockIdx.x * 128;
    const int l15 = lane & 15, l4 = lane >> 4;
    const int sr = t >> 2, kc = (t & 3) * 8;
    const int wb = wid * 512;
    float ss = 0.f;

    f32x4 acc[4][4];
#pragma unroll
    for (int i = 0; i < 4; ++i)
#pragma unroll
        for (int j = 0; j < 4; ++j) acc[i][j] = (f32x4){0.f, 0.f, 0.f, 0.f};

    for (int k0 = 0; k0 < 512; k0 += 32) {
        __syncthreads();
        {
            const float4* xp = reinterpret_cast<const float4*>(&X[(size_t)(row0 + sr) * 512 + k0 + kc]);
            float4 v0 = xp[0], v1 = xp[1];
            float xs[8] = {v0.x, v0.y, v0.z, v0.w, v1.x, v1.y, v1.z, v1.w};
            u32 hw[4], lw[4];
#pragma unroll
            for (int i = 0; i < 8; ++i) { xs[i] *= SCALE_; ss = fmaf(xs[i], xs[i], ss); }
#pragma unroll
            for (int i = 0; i < 4; ++i) {
                u16 h0, l0, h1, l1;
                split2(xs[2 * i], h0, l0); split2(xs[2 * i + 1], h1, l1);
                hw[i] = (u32)h0 | ((u32)h1 << 16);
                lw[i] = (u32)l0 | ((u32)l1 << 16);
            }
            *reinterpret_cast<uint4*>(&Ah[sr * 32 + kc]) = make_uint4(hw[0], hw[1], hw[2], hw[3]);
            *reinterpret_cast<uint4*>(&Al[sr * 32 + kc]) = make_uint4(lw[0], lw[1], lw[2], lw[3]);
            const size_t gb0 = (size_t)sr * 512 + k0 + kc;
            GLDS16(Bh_g + gb0, Bh + wb);
            GLDS16(Bl_g + gb0, Bl + wb);
            const size_t gb1 = (size_t)(128 + sr) * 512 + k0 + kc;
            GLDS16(Bh_g + gb1, Bh + 4096 + wb);
            GLDS16(Bl_g + gb1, Bl + 4096 + wb);
        }
        __syncthreads();
        bf16x8 a_h[4], a_l[4], b_h[4], b_l[4];
        const int koff = l4 * 8;
#pragma unroll
        for (int mf = 0; mf < 4; ++mf) {
            int r = (wr * 64 + mf * 16 + l15) * 32 + koff;
            a_h[mf] = *reinterpret_cast<const bf16x8*>(&Ah[r]);
            a_l[mf] = *reinterpret_cast<const bf16x8*>(&Al[r]);
        }
#pragma unroll
        for (int nf = 0; nf < 4; ++nf) {
            int r = (wc * 64 + nf * 16 + l15) * 32 + koff;
            b_h[nf] = *reinterpret_cast<const bf16x8*>(&Bh[r]);
            b_l[nf] = *reinterpret_cast<const bf16x8*>(&Bl[r]);
        }
#pragma unroll
        for (int mf = 0; mf < 4; ++mf)
#pragma unroll
            for (int nf = 0; nf < 4; ++nf) {
                acc[mf][nf] = __builtin_amdgcn_mfma_f32_16x16x32_bf16(a_h[mf], b_h[nf], acc[mf][nf], 0, 0, 0);
                acc[mf][nf] = __builtin_amdgcn_mfma_f32_16x16x32_bf16(a_h[mf], b_l[nf], acc[mf][nf], 0, 0, 0);
                acc[mf][nf] = __builtin_amdgcn_mfma_f32_16x16x32_bf16(a_l[mf], b_h[nf], acc[mf][nf], 0, 0, 0);
            }
    }
    // diag: reduce ss over the 4 staging threads of each row (consecutive lanes)
    ss += __shfl_xor(ss, 1);
    ss += __shfl_xor(ss, 2);
    if ((t & 3) == 0) diag_s[sr] = 0.5f * ss;
    __syncthreads();

    if (QPATH) {
        float rm[4][4];
#pragma unroll
        for (int mf = 0; mf < 4; ++mf)
#pragma unroll
            for (int r = 0; r < 4; ++r) {
                float v = fmaxf(fmaxf(acc[mf][0][r], acc[mf][1][r]),
                                fmaxf(acc[mf][2][r], acc[mf][3][r]));
#pragma unroll
                for (int off = 1; off < 16; off <<= 1) v = fmaxf(v, __shfl_xor(v, off));
                rm[mf][r] = v;
            }
        if (l15 == 0) {
#pragma unroll
            for (int mf = 0; mf < 4; ++mf)
#pragma unroll
                for (int r = 0; r < 4; ++r)
                    rmax[wr * 64 + mf * 16 + l4 * 4 + r][wc] = rm[mf][r];
        }
        __syncthreads();
#pragma unroll
        for (int mf = 0; mf < 4; ++mf)
#pragma unroll
            for (int r = 0; r < 4; ++r) {
                const int rl = wr * 64 + mf * 16 + l4 * 4 + r;
                float m4 = fmaxf(fmaxf(rmax[rl][0], rmax[rl][1]),
                                 fmaxf(rmax[rl][2], rmax[rl][3]));
                const float c = diag_s[rl] + m4;
#pragma unroll
                for (int nf = 0; nf < 4; ++nf) {
                    float f = expf(acc[mf][nf][r] - c) * RSQM_ + EPS_;
                    F[(size_t)(row0 + rl) * 256 + wc * 64 + nf * 16 + l15] = bfhi(f);
                }
            }
    } else {
        float bm = -1e30f;
#pragma unroll
        for (int mf = 0; mf < 4; ++mf)
#pragma unroll
            for (int r = 0; r < 4; ++r) {
                const int rl = wr * 64 + mf * 16 + l4 * 4 + r;
                const float c = diag_s[rl];
#pragma unroll
                for (int nf = 0; nf < 4; ++nf) {
                    float e = acc[mf][nf][r];
                    bm = fmaxf(bm, e);
                    F[(size_t)(row0 + rl) * 256 + wc * 64 + nf * 16 + l15] = bfhi(expf(e - c));
                }
            }
#pragma unroll
        for (int off = 1; off < 64; off <<= 1) bm = fmaxf(bm, __shfl_xor(bm, off));
        if (lane == 0) wmax[wid] = bm;
        __syncthreads();
        if (t == 0) {
            float m = wmax[0];
#pragma unroll
            for (int w = 1; w < 8; ++w) m = fmaxf(m, wmax[w]);
            atomicMax(&bmax[row0 >> 13], okey(m));
        }
    }
}

// transpose KfE [l][m] -> KfT [b][m][l] (bf16) + ksum partials over 64-l tiles
__global__ __launch_bounds__(256) void kx_t(const u16* __restrict__ KfE,
        u16* __restrict__ KfT, float* __restrict__ ksump) {
    const int mt = blockIdx.x & 3, lt = blockIdx.x >> 2;
    const int l0 = lt * 64, m0 = mt * 64, b = l0 >> 13;
    __shared__ u16 T[64][72];
    const int t = threadIdx.x;
    const int lrow = t >> 2, c0 = (t & 3) * 16;
    const uint4* src = reinterpret_cast<const uint4*>(&KfE[(size_t)(l0 + lrow) * 256 + m0 + c0]);
    uint4 u0 = src[0], u1 = src[1];
    *reinterpret_cast<uint4*>(&T[lrow][c0]) = u0;
    *reinterpret_cast<uint4*>(&T[lrow][c0 + 8]) = u1;
    __syncthreads();
    const int mloc = t >> 2, lc = (t & 3) * 16;
    u32 w[8];
    float s = 0.f;
#pragma unroll
    for (int j = 0; j < 8; ++j) {
        u16 a = T[lc + 2 * j][mloc], c = T[lc + 2 * j + 1][mloc];
        w[j] = (u32)a | ((u32)c << 16);
        s += bf2f(a) + bf2f(c);
    }
    size_t ob = ((size_t)(b * 256 + m0 + mloc)) * 8192 + (l0 & 8191) + lc;
    reinterpret_cast<uint4*>(&KfT[ob])[0] = make_uint4(w[0], w[1], w[2], w[3]);
    reinterpret_cast<uint4*>(&KfT[ob])[1] = make_uint4(w[4], w[5], w[6], w[7]);
    s += __shfl_xor(s, 1);
    s += __shfl_xor(s, 2);
    if ((t & 3) == 0) ksump[lt * 256 + m0 + mloc] = s;
}

// V fp32 [l][512] -> Vt bf16 [b][d][l] + vsum partials
__global__ __launch_bounds__(256) void split_vt(const float* __restrict__ V,
        u16* __restrict__ Vt, float* __restrict__ vsump) {
    const int dt = blockIdx.x & 7, lt = blockIdx.x >> 3;
    const int lg = lt * 64, b = lg >> 13, d0 = dt * 64;
    __shared__ u16 T[64][72];
    const int t = threadIdx.x;
    const int lrow = t >> 2, c0 = (t & 3) * 16;
#pragma unroll
    for (int ii = 0; ii < 4; ++ii) {
        float4 v = *reinterpret_cast<const float4*>(&V[(size_t)(lg + lrow) * 512 + d0 + c0 + ii * 4]);
        T[lrow][c0 + ii * 4 + 0] = bfhi(v.x);
        T[lrow][c0 + ii * 4 + 1] = bfhi(v.y);
        T[lrow][c0 + ii * 4 + 2] = bfhi(v.z);
        T[lrow][c0 + ii * 4 + 3] = bfhi(v.w);
    }
    __syncthreads();
    const int dloc = t >> 2, lc = (t & 3) * 16;
    u32 w[8];
    float s = 0.f;
#pragma unroll
    for (int j = 0; j < 8; ++j) {
        u16 a = T[lc + 2 * j][dloc], c = T[lc + 2 * j + 1][dloc];
        w[j] = (u32)a | ((u32)c << 16);
        s += bf2f(a) + bf2f(c);
    }
    size_t ob = ((size_t)(b * 512 + d0 + dloc)) * 8192 + (lg & 8191) + lc;
    reinterpret_cast<uint4*>(&Vt[ob])[0] = make_uint4(w[0], w[1], w[2], w[3]);
    reinterpret_cast<uint4*>(&Vt[ob])[1] = make_uint4(w[4], w[5], w[6], w[7]);
    s += __shfl_xor(s, 1);
    s += __shfl_xor(s, 2);
    if ((t & 3) == 0) vsump[lt * 512 + d0 + dloc] = s;
}

// Ksum_true[b][m] = e^{-bmax}*sum + L*EPS
__global__ __launch_bounds__(256) void ksum_red(const float* __restrict__ ksump,
        const u32* __restrict__ bmax, float* __restrict__ KsumT) {
    const int b = blockIdx.x, m = threadIdx.x;
    float s = 0.f;
    for (int j = 0; j < 128; ++j) s += ksump[(b * 128 + j) * 256 + m];
    const float g = expf(-odec(bmax[b]));
    KsumT[b * 256 + m] = g * s + (float)L_ * EPS_;
}

__global__ __launch_bounds__(256) void vsum_red(const float* __restrict__ vsump,
        float* __restrict__ Vsum) {
    const int idx = blockIdx.x * 256 + threadIdx.x;   // b*512+d
    const int b = idx >> 9, d = idx & 511;
    float s = 0.f;
    for (int j = 0; j < 128; ++j) s += vsump[(b * 128 + j) * 512 + d];
    Vsum[idx] = s;
}

// ---------------------------------------------------------------------------
// KV split-K GEMM (single bf16): kvp[ch][b][m][d] over 512-l chunks. 128x128,
// 256 thr (2x2 waves), grid 512, XCD-chunked swizzle.
// ---------------------------------------------------------------------------
__global__ __launch_bounds__(256) void kv_mfma(
        const u16* __restrict__ KfT, const u16* __restrict__ Vt,
        float* __restrict__ kvp) {
    int o = (blockIdx.x & 7) * 64 + (blockIdx.x >> 3);
    const int dt = o & 3, mt = (o >> 2) & 1, ch = (o >> 3) & 15, b = o >> 7;
    const u16* Ag = KfT + ((size_t)(b * 256 + mt * 128)) * 8192 + ch * 512;
    const u16* Bg = Vt + ((size_t)(b * 512 + dt * 128)) * 8192 + ch * 512;
    __shared__ __align__(16) u16 A_[128 * 32], B_[128 * 32];
    const int t = threadIdx.x, lane = t & 63;
    const int wid = t >> 6, wr = wid >> 1, wc = wid & 1;
    const int l15 = lane & 15, l4 = lane >> 4;
    const int sr2 = t >> 2, kc = (t & 3) * 8;
    f32x4 acc[4][4];
#pragma unroll
    for (int i = 0; i < 4; ++i)
#pragma unroll
        for (int j = 0; j < 4; ++j) acc[i][j] = (f32x4){0.f, 0.f, 0.f, 0.f};

    for (int k0 = 0; k0 < 512; k0 += 32) {
        __syncthreads();
#pragma unroll
        for (int it = 0; it < 2; ++it) {
            const size_t g = (size_t)(it * 64 + sr2) * 8192 + k0 + kc;
            const int dst = it * 2048 + wid * 512;
            GLDS16(Ag + g, A_ + dst);
            GLDS16(Bg + g, B_ + dst);
        }
        __syncthreads();
        bf16x8 a[4], bb[4];
        const int koff = l4 * 8;
#pragma unroll
        for (int mf = 0; mf < 4; ++mf)
            a[mf] = *reinterpret_cast<const bf16x8*>(&A_[(wr * 64 + mf * 16 + l15) * 32 + koff]);
#pragma unroll
        for (int nf = 0; nf < 4; ++nf)
            bb[nf] = *reinterpret_cast<const bf16x8*>(&B_[(wc * 64 + nf * 16 + l15) * 32 + koff]);
#pragma unroll
        for (int mf = 0; mf < 4; ++mf)
#pragma unroll
            for (int nf = 0; nf < 4; ++nf)
                acc[mf][nf] = __builtin_amdgcn_mfma_f32_16x16x32_bf16(a[mf], bb[nf], acc[mf][nf], 0, 0, 0);
    }
#pragma unroll
    for (int mf = 0; mf < 4; ++mf)
#pragma unroll
        for (int r = 0; r < 4; ++r) {
            size_t oo = ((size_t)(ch * 4 + b) * 256 + mt * 128 + wr * 64 + mf * 16 + l4 * 4 + r) * 512
                        + dt * 128 + wc * 64;
#pragma unroll
            for (int nf = 0; nf < 4; ++nf)
                kvp[oo + nf * 16 + l15] = acc[mf][nf][r];
        }
}

// reduce 16 chunks + KV_adj = gscale*KV + EPS*Vsum, split hi/lo, transpose -> KVt [b][d][m]
__global__ __launch_bounds__(256) void kv_fix(const float* __restrict__ kvp,
        const u32* __restrict__ bmax, const float* __restrict__ Vsum,
        u16* __restrict__ KVth, u16* __restrict__ KVtl) {
    const int dt = blockIdx.x & 7, mt = (blockIdx.x >> 3) & 3, b = blockIdx.x >> 5;
    const int m0 = mt * 64, d0 = dt * 64;
    __shared__ u16 Th[64][72], Tl[64][72];
    const int t = threadIdx.x, mloc = t >> 2, c0 = (t & 3) * 16;
    float s[16];
#pragma unroll
    for (int j = 0; j < 16; ++j) s[j] = 0.f;
    for (int c = 0; c < 16; ++c) {
        size_t base = ((size_t)(c * 4 + b) * 256 + m0 + mloc) * 512 + d0 + c0;
#pragma unroll
        for (int ii = 0; ii < 4; ++ii) {
            float4 v = *reinterpret_cast<const float4*>(&kvp[base + ii * 4]);
            s[ii * 4 + 0] += v.x; s[ii * 4 + 1] += v.y;
            s[ii * 4 + 2] += v.z; s[ii * 4 + 3] += v.w;
        }
    }
    const float g = expf(-odec(bmax[b]));
#pragma unroll
    for (int j = 0; j < 16; ++j) {
        float v = g * s[j] + EPS_ * Vsum[b * 512 + d0 + c0 + j];
        u16 h, l; split2(v, h, l);
        Th[mloc][c0 + j] = h;
        Tl[mloc][c0 + j] = l;
    }
    __syncthreads();
    const int dloc = t >> 2, mc = (t & 3) * 16;
    size_t ob = ((size_t)(b * 512 + d0 + dloc)) * 256 + m0 + mc;
    u32 wh[8], wl[8];
#pragma unroll
    for (int j = 0; j < 8; ++j) {
        wh[j] = (u32)Th[mc + 2 * j][dloc] | ((u32)Th[mc + 2 * j + 1][dloc] << 16);
        wl[j] = (u32)Tl[mc + 2 * j][dloc] | ((u32)Tl[mc + 2 * j + 1][dloc] << 16);
    }
    reinterpret_cast<uint4*>(&KVth[ob])[0] = make_uint4(wh[0], wh[1], wh[2], wh[3]);
    reinterpret_cast<uint4*>(&KVth[ob])[1] = make_uint4(wh[4], wh[5], wh[6], wh[7]);
    reinterpret_cast<uint4*>(&KVtl[ob])[0] = make_uint4(wl[0], wl[1], wl[2], wl[3]);
    reinterpret_cast<uint4*>(&KVtl[ob])[1] = make_uint4(wl[4], wl[5], wl[6], wl[7]);
}

// Z[row] = 1/(dot(Qf_bf16, Ksum_true[b]) + eps)
__global__ __launch_bounds__(256) void z_kernel(const u16* __restrict__ QF,
        const float* __restrict__ KsumT, float* __restrict__ Z) {
    const int wid = threadIdx.x >> 6, lane = threadIdx.x & 63;
    const int row = blockIdx.x * 4 + wid;
    const int b = row >> 13;
    uint2 u = *reinterpret_cast<const uint2*>(&QF[(size_t)row * 256 + lane * 4]);
    float4 ks = *reinterpret_cast<const float4*>(&KsumT[b * 256 + lane * 4]);
    float s = bf2f((u16)(u.x & 0xffff)) * ks.x + bf2f((u16)(u.x >> 16)) * ks.y +
              bf2f((u16)(u.y & 0xffff)) * ks.z + bf2f((u16)(u.y >> 16)) * ks.w;
#pragma unroll
    for (int off = 1; off < 64; off <<= 1) s += __shfl_xor(s, off);
    if (lane == 0) Z[row] = 1.f / (s + EPS_);
}

// out GEMM: A=Qf bf16 [row][m], B=KVt hi/lo [d][m]; 2 MFMAs; tile 128x128, K=256
__global__ __launch_bounds__(256) void out_mfma(
        const u16* __restrict__ QF, const u16* __restrict__ KVth,
        const u16* __restrict__ KVtl, const float* __restrict__ Z,
        float* __restrict__ out) {
    int o = (blockIdx.x & 7) * 128 + (blockIdx.x >> 3);
    const int dt = o & 3, rt = o >> 2;
    const int row0 = rt * 128, b = row0 >> 13;
    const u16* Ag = QF + (size_t)row0 * 256;
    const u16* Bh_g = KVth + ((size_t)(b * 512 + dt * 128)) * 256;
    const u16* Bl_g = KVtl + ((size_t)(b * 512 + dt * 128)) * 256;
    __shared__ __align__(16) u16 A_[128 * 32], Bh_[128 * 32], Bl_[128 * 32];
    const int t = threadIdx.x, lane = t & 63;
    const int wid = t >> 6, wr = wid >> 1, wc = wid & 1;
    const int l15 = lane & 15, l4 = lane >> 4;
    const int sr2 = t >> 2, kc = (t & 3) * 8;
    f32x4 acc[4][4];
#pragma unroll
    for (int i = 0; i < 4; ++i)
#pragma unroll
        for (int j = 0; j < 4; ++j) acc[i][j] = (f32x4){0.f, 0.f, 0.f, 0.f};

    for (int k0 = 0; k0 < 256; k0 += 32) {
        __syncthreads();
#pragma unroll
        for (int it = 0; it < 2; ++it) {
            const size_t g = (size_t)(it * 64 + sr2) * 256 + k0 + kc;
            const int dst = it * 2048 + wid * 512;
            GLDS16(Ag + g, A_ + dst);
            GLDS16(Bh_g + g, Bh_ + dst);
            GLDS16(Bl_g + g, Bl_ + dst);
        }
        __syncthreads();
        bf16x8 a[4], bh[4], bl[4];
        const int koff = l4 * 8;
#pragma unroll
        for (int mf = 0; mf < 4; ++mf)
            a[mf] = *reinterpret_cast<const bf16x8*>(&A_[(wr * 64 + mf * 16 + l15) * 32 + koff]);
#pragma unroll
        for (int nf = 0; nf < 4; ++nf) {
            int r = (wc * 64 + nf * 16 + l15) * 32 + koff;
            bh[nf] = *reinterpret_cast<const bf16x8*>(&Bh_[r]);
            bl[nf] = *reinterpret_cast<const bf16x8*>(&Bl_[r]);
        }
#pragma unroll
        for (int mf = 0; mf < 4; ++mf)
#pragma unroll
            for (int nf = 0; nf < 4; ++nf) {
                acc[mf][nf] = __builtin_amdgcn_mfma_f32_16x16x32_bf16(a[mf], bh[nf], acc[mf][nf], 0, 0, 0);
                acc[mf][nf] = __builtin_amdgcn_mfma_f32_16x16x32_bf16(a[mf], bl[nf], acc[mf][nf], 0, 0, 0);
            }
    }
#pragma unroll
    for (int mf = 0; mf < 4; ++mf)
#pragma unroll
        for (int r = 0; r < 4; ++r) {
            const int row = row0 + wr * 64 + mf * 16 + l4 * 4 + r;
            const float z = Z[row];
#pragma unroll
            for (int nf = 0; nf < 4; ++nf)
                out[(size_t)row * 512 + dt * 128 + wc * 64 + nf * 16 + l15] = acc[mf][nf][r] * z;
        }
}

extern "C" void kernel_launch(void* const* d_in, const int* in_sizes, int n_in,
                              void* d_out, int out_size, void* d_ws, size_t ws_size,
                              hipStream_t stream) {
    const float* Q = (const float*)d_in[0];
    const float* K = (const float*)d_in[1];
    const float* V = (const float*)d_in[2];
    const float* P = (const float*)d_in[3];
    float* out = (float*)d_out;
    char* ws = (char*)d_ws;

    u16*   QF    = (u16*)(ws + 0);             // 16 MiB
    u16*   KfE   = (u16*)(ws + 16777216);      // 16 MiB (row-major exp(dash-diag))
    u16*   KfT   = (u16*)(ws + 33554432);      // 16 MiB (transposed)
    u16*   Vt    = (u16*)(ws + 50331648);      // 32 MiB
    float* kvp   = (float*)(ws + 83886080);    // 32 MiB
    u16*   KVth  = (u16*)(ws + 117440512);     // 1 MiB
    u16*   KVtl  = (u16*)(ws + 118489088);     // 1 MiB
    u16*   PH    = (u16*)(ws + 119537664);     // 256 KiB
    u16*   PL    = (u16*)(ws + 119799808);     // 256 KiB
    float* ksump = (float*)(ws + 120061952);   // 512 KiB
    float* vsump = (float*)(ws + 120586240);   // 1 MiB
    float* KsumT = (float*)(ws + 121634816);   // 4 KiB
    float* Vsum  = (float*)(ws + 121638912);   // 8 KiB
    float* Zbuf  = (float*)(ws + 121646848);   // 128 KiB
    u32*   bmax  = (u32*)(ws + 121777664);     // 16 B

    init_k<<<1, 64, 0, stream>>>(bmax);
    split_p<<<512, 256, 0, stream>>>(P, PH, PL);
    dash_fused<1><<<256, 512, 0, stream>>>(Q, PH, PL, QF, nullptr);
    dash_fused<0><<<256, 512, 0, stream>>>(K, PH, PL, KfE, bmax);
    kx_t<<<2048, 256, 0, stream>>>(KfE, KfT, ksump);
    split_vt<<<4096, 256, 0, stream>>>(V, Vt, vsump);
    ksum_red<<<4, 256, 0, stream>>>(ksump, bmax, KsumT);
    vsum_red<<<8, 256, 0, stream>>>(vsump, Vsum);
    kv_mfma<<<512, 256, 0, stream>>>(KfT, Vt, kvp);
    kv_fix<<<128, 256, 0, stream>>>(kvp, bmax, Vsum, KVth, KVtl);
    z_kernel<<<8192, 256, 0, stream>>>(QF, KsumT, Zbuf);
    out_mfma<<<1024, 256, 0, stream>>>(QF, KVth, KVtl, Zbuf, out);
}

// Round 4
// 192.995 us; speedup vs baseline: 3.1595x; 1.0419x over previous
//
#include <hip/hip_runtime.h>
#include <math.h>

typedef unsigned short u16;
typedef unsigned int u32;
typedef __attribute__((ext_vector_type(8))) short bf16x8;
typedef __attribute__((ext_vector_type(4))) float f32x4;

#define SCALE_ 0.21022410381342864f   // 512^{-1/4}
#define EPS_ 1e-6f
#define RSQM_ 0.0625f                 // 1/sqrt(256)
#define L_ 8192

__device__ __forceinline__ u16 bfhi(float x) {
    u32 u = __float_as_uint(x);
    return (u16)((u + 0x7FFFu + ((u >> 16) & 1u)) >> 16);  // RNE bf16
}
__device__ __forceinline__ float bf2f(u16 h) {
    return __uint_as_float(((u32)h) << 16);
}
__device__ __forceinline__ void split2(float x, u16& h, u16& l) {
    h = bfhi(x);
    l = bfhi(x - bf2f(h));
}
__device__ __forceinline__ u32 okey(float x) {   // order-preserving float->u32
    u32 b = __float_as_uint(x);
    return (b & 0x80000000u) ? ~b : (b | 0x80000000u);
}
__device__ __forceinline__ float odec(u32 k) {
    return (k & 0x80000000u) ? __uint_as_float(k & 0x7fffffffu) : __uint_as_float(~k);
}

#define GLDS16(gsrc, ldst) \
    __builtin_amdgcn_global_load_lds((__attribute__((address_space(1))) void*)(gsrc), \
                                     (__attribute__((address_space(3))) void*)(ldst), 16, 0, 0)

__global__ void init_k(u32* __restrict__ bmax) {
    if (threadIdx.x < 4) bmax[threadIdx.x] = 0u;
}

__global__ __launch_bounds__(256) void split_p(const float* __restrict__ P,
        u16* __restrict__ Ph, u16* __restrict__ Pl) {
    int i = blockIdx.x * 256 + threadIdx.x;
    u16 h, l; split2(P[i], h, l);
    Ph[i] = h; Pl[i] = l;
}

// ---------------------------------------------------------------------------
// Fused dash GEMM, Q and K tiles in ONE grid-512 launch (2 blocks/CU).
// Even blocks: Q-tile (rowmax+exp -> Qf bf16). Odd: K-tile (exp(dash-diag)
// -> KfE bf16 + atomicMax bmax). Tile 128x256 (full M), 512 thr, K=512.
// A (X rows) split fp32->hi/lo in-register -> LDS; B (P) pre-split, GLDS16.
// ---------------------------------------------------------------------------
__global__ __launch_bounds__(512) void dash_all(
        const float* __restrict__ Qg, const float* __restrict__ Kg,
        const u16* __restrict__ Bh_g, const u16* __restrict__ Bl_g,
        u16* __restrict__ QF, u16* __restrict__ KfE, u32* __restrict__ bmax) {
    __shared__ __align__(16) u16 Ah[128 * 32], Al[128 * 32];
    __shared__ __align__(16) u16 Bh[256 * 32], Bl[256 * 32];
    __shared__ float rmax[128][4];
    __shared__ float diag_s[128];
    __shared__ float wmax[8];
    const int qpath = !(blockIdx.x & 1);
    const int tile = blockIdx.x >> 1;
    const float* __restrict__ X = qpath ? Qg : Kg;
    u16* __restrict__ F = qpath ? QF : KfE;
    const int t = threadIdx.x, lane = t & 63;
    const int wid = t >> 6, wr = wid >> 2, wc = wid & 3;
    const int row0 = tile * 128;
    const int l15 = lane & 15, l4 = lane >> 4;
    const int sr = t >> 2, kc = (t & 3) * 8;
    const int wb = wid * 512;
    float ss = 0.f;

    f32x4 acc[4][4];
#pragma unroll
    for (int i = 0; i < 4; ++i)
#pragma unroll
        for (int j = 0; j < 4; ++j) acc[i][j] = (f32x4){0.f, 0.f, 0.f, 0.f};

    for (int k0 = 0; k0 < 512; k0 += 32) {
        __syncthreads();
        {
            const float4* xp = reinterpret_cast<const float4*>(&X[(size_t)(row0 + sr) * 512 + k0 + kc]);
            float4 v0 = xp[0], v1 = xp[1];
            float xs[8] = {v0.x, v0.y, v0.z, v0.w, v1.x, v1.y, v1.z, v1.w};
            u32 hw[4], lw[4];
#pragma unroll
            for (int i = 0; i < 8; ++i) { xs[i] *= SCALE_; ss = fmaf(xs[i], xs[i], ss); }
#pragma unroll
            for (int i = 0; i < 4; ++i) {
                u16 h0, l0, h1, l1;
                split2(xs[2 * i], h0, l0); split2(xs[2 * i + 1], h1, l1);
                hw[i] = (u32)h0 | ((u32)h1 << 16);
                lw[i] = (u32)l0 | ((u32)l1 << 16);
            }
            *reinterpret_cast<uint4*>(&Ah[sr * 32 + kc]) = make_uint4(hw[0], hw[1], hw[2], hw[3]);
            *reinterpret_cast<uint4*>(&Al[sr * 32 + kc]) = make_uint4(lw[0], lw[1], lw[2], lw[3]);
            const size_t gb0 = (size_t)sr * 512 + k0 + kc;
            GLDS16(Bh_g + gb0, Bh + wb);
            GLDS16(Bl_g + gb0, Bl + wb);
            const size_t gb1 = (size_t)(128 + sr) * 512 + k0 + kc;
            GLDS16(Bh_g + gb1, Bh + 4096 + wb);
            GLDS16(Bl_g + gb1, Bl + 4096 + wb);
        }
        __syncthreads();
        bf16x8 a_h[4], a_l[4], b_h[4], b_l[4];
        const int koff = l4 * 8;
#pragma unroll
        for (int mf = 0; mf < 4; ++mf) {
            int r = (wr * 64 + mf * 16 + l15) * 32 + koff;
            a_h[mf] = *reinterpret_cast<const bf16x8*>(&Ah[r]);
            a_l[mf] = *reinterpret_cast<const bf16x8*>(&Al[r]);
        }
#pragma unroll
        for (int nf = 0; nf < 4; ++nf) {
            int r = (wc * 64 + nf * 16 + l15) * 32 + koff;
            b_h[nf] = *reinterpret_cast<const bf16x8*>(&Bh[r]);
            b_l[nf] = *reinterpret_cast<const bf16x8*>(&Bl[r]);
        }
#pragma unroll
        for (int mf = 0; mf < 4; ++mf)
#pragma unroll
            for (int nf = 0; nf < 4; ++nf) {
                acc[mf][nf] = __builtin_amdgcn_mfma_f32_16x16x32_bf16(a_h[mf], b_h[nf], acc[mf][nf], 0, 0, 0);
                acc[mf][nf] = __builtin_amdgcn_mfma_f32_16x16x32_bf16(a_h[mf], b_l[nf], acc[mf][nf], 0, 0, 0);
                acc[mf][nf] = __builtin_amdgcn_mfma_f32_16x16x32_bf16(a_l[mf], b_h[nf], acc[mf][nf], 0, 0, 0);
            }
    }
    // diag: reduce ss over the 4 staging threads of each row (consecutive lanes)
    ss += __shfl_xor(ss, 1);
    ss += __shfl_xor(ss, 2);
    if ((t & 3) == 0) diag_s[sr] = 0.5f * ss;
    __syncthreads();

    if (qpath) {
        float rm[4][4];
#pragma unroll
        for (int mf = 0; mf < 4; ++mf)
#pragma unroll
            for (int r = 0; r < 4; ++r) {
                float v = fmaxf(fmaxf(acc[mf][0][r], acc[mf][1][r]),
                                fmaxf(acc[mf][2][r], acc[mf][3][r]));
#pragma unroll
                for (int off = 1; off < 16; off <<= 1) v = fmaxf(v, __shfl_xor(v, off));
                rm[mf][r] = v;
            }
        if (l15 == 0) {
#pragma unroll
            for (int mf = 0; mf < 4; ++mf)
#pragma unroll
                for (int r = 0; r < 4; ++r)
                    rmax[wr * 64 + mf * 16 + l4 * 4 + r][wc] = rm[mf][r];
        }
        __syncthreads();
#pragma unroll
        for (int mf = 0; mf < 4; ++mf)
#pragma unroll
            for (int r = 0; r < 4; ++r) {
                const int rl = wr * 64 + mf * 16 + l4 * 4 + r;
                float m4 = fmaxf(fmaxf(rmax[rl][0], rmax[rl][1]),
                                 fmaxf(rmax[rl][2], rmax[rl][3]));
                const float c = diag_s[rl] + m4;
#pragma unroll
                for (int nf = 0; nf < 4; ++nf) {
                    float f = expf(acc[mf][nf][r] - c) * RSQM_ + EPS_;
                    F[(size_t)(row0 + rl) * 256 + wc * 64 + nf * 16 + l15] = bfhi(f);
                }
            }
    } else {
        float bm = -1e30f;
#pragma unroll
        for (int mf = 0; mf < 4; ++mf)
#pragma unroll
            for (int r = 0; r < 4; ++r) {
                const int rl = wr * 64 + mf * 16 + l4 * 4 + r;
                const float c = diag_s[rl];
#pragma unroll
                for (int nf = 0; nf < 4; ++nf) {
                    float e = acc[mf][nf][r];
                    bm = fmaxf(bm, e);
                    F[(size_t)(row0 + rl) * 256 + wc * 64 + nf * 16 + l15] = bfhi(expf(e - c));
                }
            }
#pragma unroll
        for (int off = 1; off < 64; off <<= 1) bm = fmaxf(bm, __shfl_xor(bm, off));
        if (lane == 0) wmax[wid] = bm;
        __syncthreads();
        if (t == 0) {
            float m = wmax[0];
#pragma unroll
            for (int w = 1; w < 8; ++w) m = fmaxf(m, wmax[w]);
            atomicMax(&bmax[row0 >> 13], okey(m));
        }
    }
}

// transpose KfE [l][m] -> KfT [b][m][l] (bf16) + ksum partials over 64-l tiles
__global__ __launch_bounds__(256) void kx_t(const u16* __restrict__ KfE,
        u16* __restrict__ KfT, float* __restrict__ ksump) {
    const int mt = blockIdx.x & 3, lt = blockIdx.x >> 2;
    const int l0 = lt * 64, m0 = mt * 64, b = l0 >> 13;
    __shared__ u16 T[64][72];
    const int t = threadIdx.x;
    const int lrow = t >> 2, c0 = (t & 3) * 16;
    const uint4* src = reinterpret_cast<const uint4*>(&KfE[(size_t)(l0 + lrow) * 256 + m0 + c0]);
    uint4 u0 = src[0], u1 = src[1];
    *reinterpret_cast<uint4*>(&T[lrow][c0]) = u0;
    *reinterpret_cast<uint4*>(&T[lrow][c0 + 8]) = u1;
    __syncthreads();
    const int mloc = t >> 2, lc = (t & 3) * 16;
    u32 w[8];
    float s = 0.f;
#pragma unroll
    for (int j = 0; j < 8; ++j) {
        u16 a = T[lc + 2 * j][mloc], c = T[lc + 2 * j + 1][mloc];
        w[j] = (u32)a | ((u32)c << 16);
        s += bf2f(a) + bf2f(c);
    }
    size_t ob = ((size_t)(b * 256 + m0 + mloc)) * 8192 + (l0 & 8191) + lc;
    reinterpret_cast<uint4*>(&KfT[ob])[0] = make_uint4(w[0], w[1], w[2], w[3]);
    reinterpret_cast<uint4*>(&KfT[ob])[1] = make_uint4(w[4], w[5], w[6], w[7]);
    s += __shfl_xor(s, 1);
    s += __shfl_xor(s, 2);
    if ((t & 3) == 0) ksump[lt * 256 + m0 + mloc] = s;
}

// V fp32 [l][512] -> Vt bf16 [b][d][l] + vsum partials
__global__ __launch_bounds__(256) void split_vt(const float* __restrict__ V,
        u16* __restrict__ Vt, float* __restrict__ vsump) {
    const int dt = blockIdx.x & 7, lt = blockIdx.x >> 3;
    const int lg = lt * 64, b = lg >> 13, d0 = dt * 64;
    __shared__ u16 T[64][72];
    const int t = threadIdx.x;
    const int lrow = t >> 2, c0 = (t & 3) * 16;
#pragma unroll
    for (int ii = 0; ii < 4; ++ii) {
        float4 v = *reinterpret_cast<const float4*>(&V[(size_t)(lg + lrow) * 512 + d0 + c0 + ii * 4]);
        T[lrow][c0 + ii * 4 + 0] = bfhi(v.x);
        T[lrow][c0 + ii * 4 + 1] = bfhi(v.y);
        T[lrow][c0 + ii * 4 + 2] = bfhi(v.z);
        T[lrow][c0 + ii * 4 + 3] = bfhi(v.w);
    }
    __syncthreads();
    const int dloc = t >> 2, lc = (t & 3) * 16;
    u32 w[8];
    float s = 0.f;
#pragma unroll
    for (int j = 0; j < 8; ++j) {
        u16 a = T[lc + 2 * j][dloc], c = T[lc + 2 * j + 1][dloc];
        w[j] = (u32)a | ((u32)c << 16);
        s += bf2f(a) + bf2f(c);
    }
    size_t ob = ((size_t)(b * 512 + d0 + dloc)) * 8192 + (lg & 8191) + lc;
    reinterpret_cast<uint4*>(&Vt[ob])[0] = make_uint4(w[0], w[1], w[2], w[3]);
    reinterpret_cast<uint4*>(&Vt[ob])[1] = make_uint4(w[4], w[5], w[6], w[7]);
    s += __shfl_xor(s, 1);
    s += __shfl_xor(s, 2);
    if ((t & 3) == 0) vsump[lt * 512 + d0 + dloc] = s;
}

// Ksum_true[b][m] = e^{-bmax}*sum + L*EPS
__global__ __launch_bounds__(256) void ksum_red(const float* __restrict__ ksump,
        const u32* __restrict__ bmax, float* __restrict__ KsumT) {
    const int b = blockIdx.x, m = threadIdx.x;
    float s = 0.f;
    for (int j = 0; j < 128; ++j) s += ksump[(b * 128 + j) * 256 + m];
    const float g = expf(-odec(bmax[b]));
    KsumT[b * 256 + m] = g * s + (float)L_ * EPS_;
}

__global__ __launch_bounds__(256) void vsum_red(const float* __restrict__ vsump,
        float* __restrict__ Vsum) {
    const int idx = blockIdx.x * 256 + threadIdx.x;   // b*512+d
    const int b = idx >> 9, d = idx & 511;
    float s = 0.f;
    for (int j = 0; j < 128; ++j) s += vsump[(b * 128 + j) * 512 + d];
    Vsum[idx] = s;
}

// ---------------------------------------------------------------------------
// KV split-K GEMM (single bf16): kvp[ch][b][m][d] over 512-l chunks.
// Tile 128x128, 512 thr (8 waves, 2m x 4d), grid 512, XCD swizzle.
// ---------------------------------------------------------------------------
__global__ __launch_bounds__(512) void kv_mfma(
        const u16* __restrict__ KfT, const u16* __restrict__ Vt,
        float* __restrict__ kvp) {
    int o = (blockIdx.x & 7) * 64 + (blockIdx.x >> 3);
    const int dt = o & 3, mt = (o >> 2) & 1, ch = (o >> 3) & 15, b = o >> 7;
    const u16* Ag = KfT + ((size_t)(b * 256 + mt * 128)) * 8192 + ch * 512;
    const u16* Bg = Vt + ((size_t)(b * 512 + dt * 128)) * 8192 + ch * 512;
    __shared__ __align__(16) u16 A_[128 * 32], B_[128 * 32];
    const int t = threadIdx.x, lane = t & 63;
    const int wid = t >> 6, wr = wid >> 2, wc = wid & 3;
    const int l15 = lane & 15, l4 = lane >> 4;
    const int sr2 = t >> 2, kc = (t & 3) * 8;
    f32x4 acc[4][2];
#pragma unroll
    for (int i = 0; i < 4; ++i)
#pragma unroll
        for (int j = 0; j < 2; ++j) acc[i][j] = (f32x4){0.f, 0.f, 0.f, 0.f};

    for (int k0 = 0; k0 < 512; k0 += 32) {
        __syncthreads();
        {
            const size_t g = (size_t)sr2 * 8192 + k0 + kc;
            GLDS16(Ag + g, A_ + wid * 512);
            GLDS16(Bg + g, B_ + wid * 512);
        }
        __syncthreads();
        bf16x8 a[4], bb[2];
        const int koff = l4 * 8;
#pragma unroll
        for (int mf = 0; mf < 4; ++mf)
            a[mf] = *reinterpret_cast<const bf16x8*>(&A_[(wr * 64 + mf * 16 + l15) * 32 + koff]);
#pragma unroll
        for (int nf = 0; nf < 2; ++nf)
            bb[nf] = *reinterpret_cast<const bf16x8*>(&B_[(wc * 32 + nf * 16 + l15) * 32 + koff]);
#pragma unroll
        for (int mf = 0; mf < 4; ++mf)
#pragma unroll
            for (int nf = 0; nf < 2; ++nf)
                acc[mf][nf] = __builtin_amdgcn_mfma_f32_16x16x32_bf16(a[mf], bb[nf], acc[mf][nf], 0, 0, 0);
    }
#pragma unroll
    for (int mf = 0; mf < 4; ++mf)
#pragma unroll
        for (int r = 0; r < 4; ++r) {
            size_t oo = ((size_t)(ch * 4 + b) * 256 + mt * 128 + wr * 64 + mf * 16 + l4 * 4 + r) * 512
                        + dt * 128 + wc * 32;
#pragma unroll
            for (int nf = 0; nf < 2; ++nf)
                kvp[oo + nf * 16 + l15] = acc[mf][nf][r];
        }
}

// reduce 16 chunks + KV_adj = gscale*KV + EPS*Vsum, split hi/lo, transpose -> KVt [b][d][m]
__global__ __launch_bounds__(256) void kv_fix(const float* __restrict__ kvp,
        const u32* __restrict__ bmax, const float* __restrict__ Vsum,
        u16* __restrict__ KVth, u16* __restrict__ KVtl) {
    const int dt = blockIdx.x & 7, mt = (blockIdx.x >> 3) & 3, b = blockIdx.x >> 5;
    const int m0 = mt * 64, d0 = dt * 64;
    __shared__ u16 Th[64][72], Tl[64][72];
    const int t = threadIdx.x, mloc = t >> 2, c0 = (t & 3) * 16;
    float s[16];
#pragma unroll
    for (int j = 0; j < 16; ++j) s[j] = 0.f;
    for (int c = 0; c < 16; ++c) {
        size_t base = ((size_t)(c * 4 + b) * 256 + m0 + mloc) * 512 + d0 + c0;
#pragma unroll
        for (int ii = 0; ii < 4; ++ii) {
            float4 v = *reinterpret_cast<const float4*>(&kvp[base + ii * 4]);
            s[ii * 4 + 0] += v.x; s[ii * 4 + 1] += v.y;
            s[ii * 4 + 2] += v.z; s[ii * 4 + 3] += v.w;
        }
    }
    const float g = expf(-odec(bmax[b]));
#pragma unroll
    for (int j = 0; j < 16; ++j) {
        float v = g * s[j] + EPS_ * Vsum[b * 512 + d0 + c0 + j];
        u16 h, l; split2(v, h, l);
        Th[mloc][c0 + j] = h;
        Tl[mloc][c0 + j] = l;
    }
    __syncthreads();
    const int dloc = t >> 2, mc = (t & 3) * 16;
    size_t ob = ((size_t)(b * 512 + d0 + dloc)) * 256 + m0 + mc;
    u32 wh[8], wl[8];
#pragma unroll
    for (int j = 0; j < 8; ++j) {
        wh[j] = (u32)Th[mc + 2 * j][dloc] | ((u32)Th[mc + 2 * j + 1][dloc] << 16);
        wl[j] = (u32)Tl[mc + 2 * j][dloc] | ((u32)Tl[mc + 2 * j + 1][dloc] << 16);
    }
    reinterpret_cast<uint4*>(&KVth[ob])[0] = make_uint4(wh[0], wh[1], wh[2], wh[3]);
    reinterpret_cast<uint4*>(&KVth[ob])[1] = make_uint4(wh[4], wh[5], wh[6], wh[7]);
    reinterpret_cast<uint4*>(&KVtl[ob])[0] = make_uint4(wl[0], wl[1], wl[2], wl[3]);
    reinterpret_cast<uint4*>(&KVtl[ob])[1] = make_uint4(wl[4], wl[5], wl[6], wl[7]);
}

// Z[row] = 1/(dot(Qf_bf16, Ksum_true[b]) + eps)
__global__ __launch_bounds__(256) void z_kernel(const u16* __restrict__ QF,
        const float* __restrict__ KsumT, float* __restrict__ Z) {
    const int wid = threadIdx.x >> 6, lane = threadIdx.x & 63;
    const int row = blockIdx.x * 4 + wid;
    const int b = row >> 13;
    uint2 u = *reinterpret_cast<const uint2*>(&QF[(size_t)row * 256 + lane * 4]);
    float4 ks = *reinterpret_cast<const float4*>(&KsumT[b * 256 + lane * 4]);
    float s = bf2f((u16)(u.x & 0xffff)) * ks.x + bf2f((u16)(u.x >> 16)) * ks.y +
              bf2f((u16)(u.y & 0xffff)) * ks.z + bf2f((u16)(u.y >> 16)) * ks.w;
#pragma unroll
    for (int off = 1; off < 64; off <<= 1) s += __shfl_xor(s, off);
    if (lane == 0) Z[row] = 1.f / (s + EPS_);
}

// ---------------------------------------------------------------------------
// out GEMM: out[row][d] = Z[row]*sum_m Qf[row][m]*KVt[d][m].
// Tile 256(row) x 128(d), 512 thr (8 waves, 4r x 2d), grid 512, XCD swizzle.
// ---------------------------------------------------------------------------
__global__ __launch_bounds__(512) void out_mfma(
        const u16* __restrict__ QF, const u16* __restrict__ KVth,
        const u16* __restrict__ KVtl, const float* __restrict__ Z,
        float* __restrict__ out) {
    int o = (blockIdx.x & 7) * 64 + (blockIdx.x >> 3);
    const int dt = o & 3, rt = o >> 2;
    const int row0 = rt * 256, b = row0 >> 13;
    const u16* Ag = QF + (size_t)row0 * 256;
    const u16* Bh_g = KVth + ((size_t)(b * 512 + dt * 128)) * 256;
    const u16* Bl_g = KVtl + ((size_t)(b * 512 + dt * 128)) * 256;
    __shared__ __align__(16) u16 A_[256 * 32], Bh_[128 * 32], Bl_[128 * 32];
    const int t = threadIdx.x, lane = t & 63;
    const int wid = t >> 6, wr = wid >> 1, wc = wid & 1;
    const int l15 = lane & 15, l4 = lane >> 4;
    const int sr2 = t >> 2, kc = (t & 3) * 8;
    f32x4 acc[4][4];
#pragma unroll
    for (int i = 0; i < 4; ++i)
#pragma unroll
        for (int j = 0; j < 4; ++j) acc[i][j] = (f32x4){0.f, 0.f, 0.f, 0.f};

    for (int k0 = 0; k0 < 256; k0 += 32) {
        __syncthreads();
        {
            const size_t g0 = (size_t)sr2 * 256 + k0 + kc;
            GLDS16(Ag + g0, A_ + wid * 512);
            const size_t g1 = (size_t)(128 + sr2) * 256 + k0 + kc;
            GLDS16(Ag + g1, A_ + 4096 + wid * 512);
            GLDS16(Bh_g + g0, Bh_ + wid * 512);
            GLDS16(Bl_g + g0, Bl_ + wid * 512);
        }
        __syncthreads();
        bf16x8 a[4], bh[4], bl[4];
        const int koff = l4 * 8;
#pragma unroll
        for (int mf = 0; mf < 4; ++mf)
            a[mf] = *reinterpret_cast<const bf16x8*>(&A_[(wr * 64 + mf * 16 + l15) * 32 + koff]);
#pragma unroll
        for (int nf = 0; nf < 4; ++nf) {
            int r = (wc * 64 + nf * 16 + l15) * 32 + koff;
            bh[nf] = *reinterpret_cast<const bf16x8*>(&Bh_[r]);
            bl[nf] = *reinterpret_cast<const bf16x8*>(&Bl_[r]);
        }
#pragma unroll
        for (int mf = 0; mf < 4; ++mf)
#pragma unroll
            for (int nf = 0; nf < 4; ++nf) {
                acc[mf][nf] = __builtin_amdgcn_mfma_f32_16x16x32_bf16(a[mf], bh[nf], acc[mf][nf], 0, 0, 0);
                acc[mf][nf] = __builtin_amdgcn_mfma_f32_16x16x32_bf16(a[mf], bl[nf], acc[mf][nf], 0, 0, 0);
            }
    }
#pragma unroll
    for (int mf = 0; mf < 4; ++mf)
#pragma unroll
        for (int r = 0; r < 4; ++r) {
            const int row = row0 + wr * 64 + mf * 16 + l4 * 4 + r;
            const float z = Z[row];
#pragma unroll
            for (int nf = 0; nf < 4; ++nf)
                out[(size_t)row * 512 + dt * 128 + wc * 64 + nf * 16 + l15] = acc[mf][nf][r] * z;
        }
}

extern "C" void kernel_launch(void* const* d_in, const int* in_sizes, int n_in,
                              void* d_out, int out_size, void* d_ws, size_t ws_size,
                              hipStream_t stream) {
    const float* Q = (const float*)d_in[0];
    const float* K = (const float*)d_in[1];
    const float* V = (const float*)d_in[2];
    const float* P = (const float*)d_in[3];
    float* out = (float*)d_out;
    char* ws = (char*)d_ws;

    u16*   QF    = (u16*)(ws + 0);             // 16 MiB
    u16*   KfE   = (u16*)(ws + 16777216);      // 16 MiB (row-major exp(dash-diag))
    u16*   KfT   = (u16*)(ws + 33554432);      // 16 MiB (transposed)
    u16*   Vt    = (u16*)(ws + 50331648);      // 32 MiB
    float* kvp   = (float*)(ws + 83886080);    // 32 MiB
    u16*   KVth  = (u16*)(ws + 117440512);     // 1 MiB
    u16*   KVtl  = (u16*)(ws + 118489088);     // 1 MiB
    u16*   PH    = (u16*)(ws + 119537664);     // 256 KiB
    u16*   PL    = (u16*)(ws + 119799808);     // 256 KiB
    float* ksump = (float*)(ws + 120061952);   // 512 KiB
    float* vsump = (float*)(ws + 120586240);   // 1 MiB
    float* KsumT = (float*)(ws + 121634816);   // 4 KiB
    float* Vsum  = (float*)(ws + 121638912);   // 8 KiB
    float* Zbuf  = (float*)(ws + 121646848);   // 128 KiB
    u32*   bmax  = (u32*)(ws + 121777664);     // 16 B

    init_k<<<1, 64, 0, stream>>>(bmax);
    split_p<<<512, 256, 0, stream>>>(P, PH, PL);
    dash_all<<<512, 512, 0, stream>>>(Q, K, PH, PL, QF, KfE, bmax);
    kx_t<<<2048, 256, 0, stream>>>(KfE, KfT, ksump);
    split_vt<<<4096, 256, 0, stream>>>(V, Vt, vsump);
    ksum_red<<<4, 256, 0, stream>>>(ksump, bmax, KsumT);
    vsum_red<<<8, 256, 0, stream>>>(vsump, Vsum);
    kv_mfma<<<512, 512, 0, stream>>>(KfT, Vt, kvp);
    kv_fix<<<128, 256, 0, stream>>>(kvp, bmax, Vsum, KVth, KVtl);
    z_kernel<<<8192, 256, 0, stream>>>(QF, KsumT, Zbuf);
    out_mfma<<<512, 512, 0, stream>>>(QF, KVth, KVtl, Zbuf, out);
}